// Round 1
// baseline (2548.414 us; speedup 1.0000x reference)
//
#include <hip/hip_runtime.h>
#include <hip/hip_bf16.h>

#define N_NODES   40000
#define N_EDGES   640000
#define IN_CH     128
#define HID1      512
#define HID2      256
#define OUT_CH    2
#define NUM_GRAPHS 16
#define EPSF      1e-5f

// ---------------- degree + norm ----------------
__global__ __launch_bounds__(256) void deg_kernel(const int* __restrict__ dst,
                                                  const float* __restrict__ ew,
                                                  float* __restrict__ deg) {
    int t = blockIdx.x * blockDim.x + threadIdx.x;
    if (t < N_EDGES) {
        atomicAdd(&deg[dst[t]], ew[t]);
    } else if (t < N_EDGES + N_NODES) {
        atomicAdd(&deg[t - N_EDGES], 1.0f);   // self-loop weight 1
    }
}

__global__ __launch_bounds__(256) void dinv_kernel(const float* __restrict__ deg,
                                                   float* __restrict__ dinv) {
    int t = blockIdx.x * blockDim.x + threadIdx.x;
    if (t < N_NODES) {
        float d = deg[t];
        dinv[t] = d > 0.0f ? rsqrtf(d) : 0.0f;
    }
}

// ---------------- GEMM 1: [N,128] @ [128,512] ----------------
__global__ __launch_bounds__(256) void gemm1_kernel(const float* __restrict__ A,
                                                    const float* __restrict__ B,
                                                    float* __restrict__ C) {
    __shared__ float As[8 * IN_CH];
    const int row0 = blockIdx.x * 8;
    const int t = threadIdx.x;
#pragma unroll
    for (int j = 0; j < 4; ++j) {
        int idx = t + j * 256;                  // 8*128 = 1024 contiguous floats
        As[idx] = A[(size_t)row0 * IN_CH + idx];
    }
    __syncthreads();
    float acc[8][2] = {};
    const int c0 = t * 2;
    for (int k = 0; k < IN_CH; ++k) {
        float2 b = *(const float2*)&B[(size_t)k * HID1 + c0];
#pragma unroll
        for (int r = 0; r < 8; ++r) {
            float a = As[r * IN_CH + k];
            acc[r][0] += a * b.x;
            acc[r][1] += a * b.y;
        }
    }
#pragma unroll
    for (int r = 0; r < 8; ++r) {
        float2 o = { acc[r][0], acc[r][1] };
        *(float2*)&C[(size_t)(row0 + r) * HID1 + c0] = o;
    }
}

// ---------------- GEMM 2: [N,512] @ [512,256] ----------------
__global__ __launch_bounds__(256) void gemm2_kernel(const float* __restrict__ A,
                                                    const float* __restrict__ B,
                                                    float* __restrict__ C) {
    __shared__ float As[8 * HID1];
    const int row0 = blockIdx.x * 8;
    const int t = threadIdx.x;
#pragma unroll
    for (int j = 0; j < 16; ++j) {
        int idx = t + j * 256;                  // 8*512 = 4096 contiguous floats
        As[idx] = A[(size_t)row0 * HID1 + idx];
    }
    __syncthreads();
    float acc[8] = {};
    for (int k = 0; k < HID1; ++k) {
        float b = B[(size_t)k * HID2 + t];
#pragma unroll
        for (int r = 0; r < 8; ++r)
            acc[r] += As[r * HID1 + k] * b;
    }
#pragma unroll
    for (int r = 0; r < 8; ++r)
        C[(size_t)(row0 + r) * HID2 + t] = acc[r];
}

// ---------------- edge aggregation (one wave per edge) ----------------
template <int C>
__global__ __launch_bounds__(256) void agg_kernel(const int* __restrict__ srcArr,
                                                  const int* __restrict__ dstArr,
                                                  const float* __restrict__ ew,
                                                  const float* __restrict__ dinv,
                                                  const float* __restrict__ xw,
                                                  float* __restrict__ agg) {
    const int wv = (blockIdx.x * blockDim.x + threadIdx.x) >> 6;
    const int lane = threadIdx.x & 63;
    if (wv >= N_EDGES + N_NODES) return;
    int s, d; float w;
    if (wv < N_EDGES) { s = srcArr[wv]; d = dstArr[wv]; w = ew[wv]; }
    else { s = d = wv - N_EDGES; w = 1.0f; }
    const float norm = dinv[s] * w * dinv[d];
    const float* __restrict__ xs = xw + (size_t)s * C;
    float* __restrict__ ad = agg + (size_t)d * C;
#pragma unroll
    for (int j = 0; j < C / 64; ++j) {
        int c = lane + 64 * j;
        atomicAdd(&ad[c], norm * xs[c]);
    }
}

// ---------------- bias + ReLU + LayerNorm (wave per row, in place) ----------------
template <int C>
__global__ __launch_bounds__(256) void relu_ln_kernel(float* __restrict__ io,
                                                      const float* __restrict__ bias,
                                                      const float* __restrict__ g,
                                                      const float* __restrict__ be) {
    const int wv = (blockIdx.x * blockDim.x + threadIdx.x) >> 6;
    const int lane = threadIdx.x & 63;
    if (wv >= N_NODES) return;
    float* __restrict__ row = io + (size_t)wv * C;
    float v[C / 64];
    float sum = 0.f, sq = 0.f;
#pragma unroll
    for (int j = 0; j < C / 64; ++j) {
        int c = lane + 64 * j;
        float x = row[c] + bias[c];
        x = fmaxf(x, 0.f);
        v[j] = x;
        sum += x;
        sq += x * x;
    }
#pragma unroll
    for (int off = 32; off >= 1; off >>= 1) {
        sum += __shfl_xor(sum, off);
        sq  += __shfl_xor(sq, off);
    }
    const float mean = sum * (1.0f / C);
    const float var = sq * (1.0f / C) - mean * mean;
    const float r = rsqrtf(var + EPSF);
#pragma unroll
    for (int j = 0; j < C / 64; ++j) {
        int c = lane + 64 * j;
        row[c] = (v[j] - mean) * r * g[c] + be[c];
    }
}

// ---------------- global mean pool (atomics) ----------------
__global__ __launch_bounds__(256) void pool_kernel(const float* __restrict__ h3,
                                                   const int* __restrict__ batch,
                                                   float* __restrict__ pooled,
                                                   float* __restrict__ counts) {
    const int wv = (blockIdx.x * blockDim.x + threadIdx.x) >> 6;
    const int lane = threadIdx.x & 63;
    if (wv >= N_NODES) return;
    const int gid = batch[wv];
    const float* __restrict__ row = h3 + (size_t)wv * HID2;
#pragma unroll
    for (int j = 0; j < 4; ++j) {
        int c = lane + 64 * j;
        atomicAdd(&pooled[gid * HID2 + c], row[c]);
    }
    if (lane == 0) atomicAdd(&counts[gid], 1.0f);
}

// ---------------- final FC ----------------
__global__ __launch_bounds__(64) void fc_kernel(const float* __restrict__ pooled,
                                                const float* __restrict__ counts,
                                                const float* __restrict__ Wfc,
                                                const float* __restrict__ bfc,
                                                float* __restrict__ out) {
    const int t = threadIdx.x;
    if (t >= NUM_GRAPHS * OUT_CH) return;
    const int gid = t / OUT_CH;
    const int o = t % OUT_CH;
    const float inv = 1.0f / fmaxf(counts[gid], 1.0f);
    float s = 0.f;
    for (int k = 0; k < HID2; ++k)
        s += pooled[gid * HID2 + k] * inv * Wfc[k * OUT_CH + o];
    out[t] = s + bfc[o];
}

extern "C" void kernel_launch(void* const* d_in, const int* in_sizes, int n_in,
                              void* d_out, int out_size, void* d_ws, size_t ws_size,
                              hipStream_t stream) {
    const float* x   = (const float*)d_in[0];
    const int*   ei  = (const int*)d_in[1];          // [2, E] flat
    const float* ew  = (const float*)d_in[2];
    const int*   bat = (const int*)d_in[3];
    const float* W1  = (const float*)d_in[4];
    const float* b1  = (const float*)d_in[5];
    const float* g1  = (const float*)d_in[6];
    const float* be1 = (const float*)d_in[7];
    const float* W2  = (const float*)d_in[8];
    const float* b2  = (const float*)d_in[9];
    const float* g2  = (const float*)d_in[10];
    const float* be2 = (const float*)d_in[11];
    const float* Wfc = (const float*)d_in[12];
    const float* bfc = (const float*)d_in[13];

    const int* srcArr = ei;
    const int* dstArr = ei + N_EDGES;

    float* out = (float*)d_out;
    float* h3  = out;                       // [40000, 256]
    float* fcO = out + (size_t)N_NODES * HID2;

    // workspace layout (f32 elements)
    float* ws = (float*)d_ws;
    float* deg    = ws;                                   // 40960 (padded)
    float* dinv   = deg + 40960;                          // 40960
    float* bufA   = dinv + 40960;                         // N*512 (xw, then hw)
    float* bufB   = bufA + (size_t)N_NODES * HID1;        // N*512 (agg1 / h)
    float* pooled = bufB + (size_t)N_NODES * HID1;        // 16*256
    float* counts = pooled + NUM_GRAPHS * HID2;           // 16

    // 1. degree
    hipMemsetAsync(deg, 0, N_NODES * sizeof(float), stream);
    {
        int total = N_EDGES + N_NODES;
        deg_kernel<<<(total + 255) / 256, 256, 0, stream>>>(dstArr, ew, deg);
    }
    dinv_kernel<<<(N_NODES + 255) / 256, 256, 0, stream>>>(deg, dinv);

    // 2. layer 1: xw = x @ W1
    gemm1_kernel<<<N_NODES / 8, 256, 0, stream>>>(x, W1, bufA);

    // 3. aggregate into bufB
    hipMemsetAsync(bufB, 0, (size_t)N_NODES * HID1 * sizeof(float), stream);
    {
        int waves = N_EDGES + N_NODES;
        agg_kernel<HID1><<<(waves + 3) / 4, 256, 0, stream>>>(srcArr, dstArr, ew, dinv, bufA, bufB);
    }

    // 4. bias + relu + LN (in place -> h)
    relu_ln_kernel<HID1><<<(N_NODES + 3) / 4, 256, 0, stream>>>(bufB, b1, g1, be1);

    // 5. layer 2: hw = h @ W2 (reuse bufA)
    gemm2_kernel<<<N_NODES / 8, 256, 0, stream>>>(bufB, W2, bufA);

    // 6. aggregate into d_out (h3 region)
    hipMemsetAsync(h3, 0, (size_t)N_NODES * HID2 * sizeof(float), stream);
    {
        int waves = N_EDGES + N_NODES;
        agg_kernel<HID2><<<(waves + 3) / 4, 256, 0, stream>>>(srcArr, dstArr, ew, dinv, bufA, h3);
    }

    // 7. bias + relu + LN (in place -> h3)
    relu_ln_kernel<HID2><<<(N_NODES + 3) / 4, 256, 0, stream>>>(h3, b2, g2, be2);

    // 8. pool + fc
    hipMemsetAsync(pooled, 0, (NUM_GRAPHS * HID2 + NUM_GRAPHS) * sizeof(float), stream);
    pool_kernel<<<(N_NODES + 3) / 4, 256, 0, stream>>>(h3, bat, pooled, counts);
    fc_kernel<<<1, 64, 0, stream>>>(pooled, counts, Wfc, bfc, fcO);
}

// Round 2
// 1243.664 us; speedup vs baseline: 2.0491x; 2.0491x over previous
//
#include <hip/hip_runtime.h>
#include <hip/hip_bf16.h>

#define N_NODES   40000
#define N_EDGES   640000
#define IN_CH     128
#define HID1      512
#define HID2      256
#define OUT_CH    2
#define NUM_GRAPHS 16
#define EPSF      1e-5f

// ---------------- degree (weighted) + in-degree count ----------------
__global__ __launch_bounds__(256) void degcnt_kernel(const int* __restrict__ dst,
                                                     const float* __restrict__ ew,
                                                     float* __restrict__ deg,
                                                     int* __restrict__ cnt) {
    int t = blockIdx.x * blockDim.x + threadIdx.x;
    if (t < N_EDGES) {
        int d = dst[t];
        atomicAdd(&deg[d], ew[t]);
        atomicAdd(&cnt[d], 1);
    }
}

__global__ __launch_bounds__(256) void dinv_kernel(const float* __restrict__ deg,
                                                   float* __restrict__ dinv) {
    int t = blockIdx.x * blockDim.x + threadIdx.x;
    if (t < N_NODES) {
        // self-loop adds weight 1 -> deg_total = deg + 1 >= 1 > 0 always
        dinv[t] = rsqrtf(deg[t] + 1.0f);
    }
}

// ---------------- exclusive prefix sum over cnt -> rowptr (single block) ----
__global__ __launch_bounds__(1024) void scan_kernel(const int* __restrict__ cnt,
                                                    int* __restrict__ rowptr) {
    __shared__ int partial[1024];
    const int t = threadIdx.x;
    const int base = t * 40;                 // 1024*40 = 40960 >= N_NODES
    int s = 0;
    for (int i = 0; i < 40; ++i) {
        int idx = base + i;
        if (idx < N_NODES) s += cnt[idx];
    }
    partial[t] = s;
    __syncthreads();
    // Hillis-Steele inclusive scan
    for (int off = 1; off < 1024; off <<= 1) {
        int v = 0;
        if (t >= off) v = partial[t - off];
        __syncthreads();
        if (t >= off) partial[t] += v;
        __syncthreads();
    }
    int run = (t == 0) ? 0 : partial[t - 1];
    for (int i = 0; i < 40; ++i) {
        int idx = base + i;
        if (idx < N_NODES) {
            rowptr[idx] = run;
            run += cnt[idx];
        }
    }
    if (t == 0) rowptr[N_NODES] = N_EDGES;
}

// ---------------- scatter edges into CSR (by dst) ----------------
__global__ __launch_bounds__(256) void scatter_kernel(const int* __restrict__ src,
                                                      const int* __restrict__ dst,
                                                      const float* __restrict__ ew,
                                                      const float* __restrict__ dinv,
                                                      const int* __restrict__ rowptr,
                                                      int* __restrict__ cursor,
                                                      int* __restrict__ csr_src,
                                                      float* __restrict__ csr_norm) {
    int t = blockIdx.x * blockDim.x + threadIdx.x;
    if (t >= N_EDGES) return;
    int s = src[t], d = dst[t];
    int pos = rowptr[d] + atomicAdd(&cursor[d], 1);
    csr_src[pos] = s;
    csr_norm[pos] = dinv[s] * ew[t] * dinv[d];
}

// ---------------- CSR aggregation: out[i] = dinv[i]^2*feat[i] + sum norm*feat[src]
template <int C>
__global__ __launch_bounds__(256) void agg_csr_kernel(const int* __restrict__ rowptr,
                                                      const int* __restrict__ csr_src,
                                                      const float* __restrict__ csr_norm,
                                                      const float* __restrict__ dinv,
                                                      const float* __restrict__ feat,
                                                      float* __restrict__ out) {
    const int node = (blockIdx.x * blockDim.x + threadIdx.x) >> 6;
    const int lane = threadIdx.x & 63;
    if (node >= N_NODES) return;

    const float ds = dinv[node];
    const float wself = ds * ds;
    const int e0 = rowptr[node], e1 = rowptr[node + 1];

    if constexpr (C == 128) {
        const int c0 = lane * 2;
        float2 v = *(const float2*)&feat[(size_t)node * C + c0];
        float2 acc = { wself * v.x, wself * v.y };
        for (int e = e0; e < e1; ++e) {
            int s = csr_src[e];
            float w = csr_norm[e];
            float2 u = *(const float2*)&feat[(size_t)s * C + c0];
            acc.x += w * u.x;
            acc.y += w * u.y;
        }
        *(float2*)&out[(size_t)node * C + c0] = acc;
    } else {
        const int c0 = lane * 4;
        float4 v = *(const float4*)&feat[(size_t)node * C + c0];
        float4 acc = { wself * v.x, wself * v.y, wself * v.z, wself * v.w };
        for (int e = e0; e < e1; ++e) {
            int s = csr_src[e];
            float w = csr_norm[e];
            float4 u = *(const float4*)&feat[(size_t)s * C + c0];
            acc.x += w * u.x;
            acc.y += w * u.y;
            acc.z += w * u.z;
            acc.w += w * u.w;
        }
        *(float4*)&out[(size_t)node * C + c0] = acc;
    }
}

// ---------------- GEMM 1: [N,128] @ [128,512] ----------------
__global__ __launch_bounds__(256) void gemm1_kernel(const float* __restrict__ A,
                                                    const float* __restrict__ B,
                                                    float* __restrict__ C) {
    __shared__ float As[8 * IN_CH];
    const int row0 = blockIdx.x * 8;
    const int t = threadIdx.x;
#pragma unroll
    for (int j = 0; j < 4; ++j) {
        int idx = t + j * 256;
        As[idx] = A[(size_t)row0 * IN_CH + idx];
    }
    __syncthreads();
    float acc[8][2] = {};
    const int c0 = t * 2;
    for (int k = 0; k < IN_CH; ++k) {
        float2 b = *(const float2*)&B[(size_t)k * HID1 + c0];
#pragma unroll
        for (int r = 0; r < 8; ++r) {
            float a = As[r * IN_CH + k];
            acc[r][0] += a * b.x;
            acc[r][1] += a * b.y;
        }
    }
#pragma unroll
    for (int r = 0; r < 8; ++r) {
        float2 o = { acc[r][0], acc[r][1] };
        *(float2*)&C[(size_t)(row0 + r) * HID1 + c0] = o;
    }
}

// ---------------- GEMM 2: [N,512] @ [512,256] ----------------
__global__ __launch_bounds__(256) void gemm2_kernel(const float* __restrict__ A,
                                                    const float* __restrict__ B,
                                                    float* __restrict__ C) {
    __shared__ float As[8 * HID1];
    const int row0 = blockIdx.x * 8;
    const int t = threadIdx.x;
#pragma unroll
    for (int j = 0; j < 16; ++j) {
        int idx = t + j * 256;
        As[idx] = A[(size_t)row0 * HID1 + idx];
    }
    __syncthreads();
    float acc[8] = {};
    for (int k = 0; k < HID1; ++k) {
        float b = B[(size_t)k * HID2 + t];
#pragma unroll
        for (int r = 0; r < 8; ++r)
            acc[r] += As[r * HID1 + k] * b;
    }
#pragma unroll
    for (int r = 0; r < 8; ++r)
        C[(size_t)(row0 + r) * HID2 + t] = acc[r];
}

// ---------------- bias + ReLU + LayerNorm (wave per row, in place) ----------------
template <int C>
__global__ __launch_bounds__(256) void relu_ln_kernel(float* __restrict__ io,
                                                      const float* __restrict__ bias,
                                                      const float* __restrict__ g,
                                                      const float* __restrict__ be) {
    const int wv = (blockIdx.x * blockDim.x + threadIdx.x) >> 6;
    const int lane = threadIdx.x & 63;
    if (wv >= N_NODES) return;
    float* __restrict__ row = io + (size_t)wv * C;
    float v[C / 64];
    float sum = 0.f, sq = 0.f;
#pragma unroll
    for (int j = 0; j < C / 64; ++j) {
        int c = lane + 64 * j;
        float x = row[c] + bias[c];
        x = fmaxf(x, 0.f);
        v[j] = x;
        sum += x;
        sq += x * x;
    }
#pragma unroll
    for (int off = 32; off >= 1; off >>= 1) {
        sum += __shfl_xor(sum, off);
        sq  += __shfl_xor(sq, off);
    }
    const float mean = sum * (1.0f / C);
    const float var = sq * (1.0f / C) - mean * mean;
    const float r = rsqrtf(var + EPSF);
#pragma unroll
    for (int j = 0; j < C / 64; ++j) {
        int c = lane + 64 * j;
        row[c] = (v[j] - mean) * r * g[c] + be[c];
    }
}

// ---------------- global mean pool (atomics) ----------------
__global__ __launch_bounds__(256) void pool_kernel(const float* __restrict__ h3,
                                                   const int* __restrict__ batch,
                                                   float* __restrict__ pooled,
                                                   float* __restrict__ counts) {
    const int wv = (blockIdx.x * blockDim.x + threadIdx.x) >> 6;
    const int lane = threadIdx.x & 63;
    if (wv >= N_NODES) return;
    const int gid = batch[wv];
    const float* __restrict__ row = h3 + (size_t)wv * HID2;
#pragma unroll
    for (int j = 0; j < 4; ++j) {
        int c = lane + 64 * j;
        atomicAdd(&pooled[gid * HID2 + c], row[c]);
    }
    if (lane == 0) atomicAdd(&counts[gid], 1.0f);
}

// ---------------- final FC ----------------
__global__ __launch_bounds__(64) void fc_kernel(const float* __restrict__ pooled,
                                                const float* __restrict__ counts,
                                                const float* __restrict__ Wfc,
                                                const float* __restrict__ bfc,
                                                float* __restrict__ out) {
    const int t = threadIdx.x;
    if (t >= NUM_GRAPHS * OUT_CH) return;
    const int gid = t / OUT_CH;
    const int o = t % OUT_CH;
    const float inv = 1.0f / fmaxf(counts[gid], 1.0f);
    float s = 0.f;
    for (int k = 0; k < HID2; ++k)
        s += pooled[gid * HID2 + k] * inv * Wfc[k * OUT_CH + o];
    out[t] = s + bfc[o];
}

extern "C" void kernel_launch(void* const* d_in, const int* in_sizes, int n_in,
                              void* d_out, int out_size, void* d_ws, size_t ws_size,
                              hipStream_t stream) {
    const float* x   = (const float*)d_in[0];
    const int*   ei  = (const int*)d_in[1];
    const float* ew  = (const float*)d_in[2];
    const int*   bat = (const int*)d_in[3];
    const float* W1  = (const float*)d_in[4];
    const float* b1  = (const float*)d_in[5];
    const float* g1  = (const float*)d_in[6];
    const float* be1 = (const float*)d_in[7];
    const float* W2  = (const float*)d_in[8];
    const float* b2  = (const float*)d_in[9];
    const float* g2  = (const float*)d_in[10];
    const float* be2 = (const float*)d_in[11];
    const float* Wfc = (const float*)d_in[12];
    const float* bfc = (const float*)d_in[13];

    const int* srcArr = ei;
    const int* dstArr = ei + N_EDGES;

    float* out = (float*)d_out;
    float* h3  = out;                       // [40000, 256]
    float* fcO = out + (size_t)N_NODES * HID2;

    // workspace layout (f32/int32 elements)
    float* ws       = (float*)d_ws;
    float* deg      = ws;                              // 40960
    int*   cnt      = (int*)(deg + 40960);             // 40960
    int*   cursor   = cnt + 40960;                     // 40960
    float* dinv     = (float*)(cursor + 40960);        // 40960
    int*   rowptr   = (int*)(dinv + 40960);            // 41024 (pad)
    int*   csr_src  = rowptr + 41024;                  // 640000
    float* csr_norm = (float*)(csr_src + N_EDGES);     // 640000
    float* agg1     = csr_norm + N_EDGES;              // N*128
    float* h        = agg1 + (size_t)N_NODES * IN_CH;  // N*512
    float* hw       = h + (size_t)N_NODES * HID1;      // N*256
    float* pooled   = hw + (size_t)N_NODES * HID2;     // 16*256
    float* counts   = pooled + NUM_GRAPHS * HID2;      // 16

    // 1. zero deg+cnt+cursor (contiguous 3*40960 words)
    hipMemsetAsync(deg, 0, 3 * 40960 * sizeof(float), stream);
    degcnt_kernel<<<(N_EDGES + 255) / 256, 256, 0, stream>>>(dstArr, ew, deg, cnt);
    dinv_kernel<<<(N_NODES + 255) / 256, 256, 0, stream>>>(deg, dinv);

    // 2. CSR build
    scan_kernel<<<1, 1024, 0, stream>>>(cnt, rowptr);
    scatter_kernel<<<(N_EDGES + 255) / 256, 256, 0, stream>>>(
        srcArr, dstArr, ew, dinv, rowptr, cursor, csr_src, csr_norm);

    // 3. layer 1: agg1 = A_norm @ x  (128 ch), then h = agg1 @ W1
    agg_csr_kernel<IN_CH><<<(N_NODES + 3) / 4, 256, 0, stream>>>(
        rowptr, csr_src, csr_norm, dinv, x, agg1);
    gemm1_kernel<<<N_NODES / 8, 256, 0, stream>>>(agg1, W1, h);
    relu_ln_kernel<HID1><<<(N_NODES + 3) / 4, 256, 0, stream>>>(h, b1, g1, be1);

    // 4. layer 2: hw = h @ W2 (256 ch), then h3 = A_norm @ hw
    gemm2_kernel<<<N_NODES / 8, 256, 0, stream>>>(h, W2, hw);
    agg_csr_kernel<HID2><<<(N_NODES + 3) / 4, 256, 0, stream>>>(
        rowptr, csr_src, csr_norm, dinv, hw, h3);
    relu_ln_kernel<HID2><<<(N_NODES + 3) / 4, 256, 0, stream>>>(h3, b2, g2, be2);

    // 5. pool + fc
    hipMemsetAsync(pooled, 0, (NUM_GRAPHS * HID2 + NUM_GRAPHS) * sizeof(float), stream);
    pool_kernel<<<(N_NODES + 3) / 4, 256, 0, stream>>>(h3, bat, pooled, counts);
    fc_kernel<<<1, 64, 0, stream>>>(pooled, counts, Wfc, bfc, fcO);
}

// Round 3
// 467.418 us; speedup vs baseline: 5.4521x; 2.6607x over previous
//
#include <hip/hip_runtime.h>
#include <hip/hip_bf16.h>

#define N_NODES   40000
#define N_EDGES   640000
#define IN_CH     128
#define HID1      512
#define HID2      256
#define OUT_CH    2
#define NUM_GRAPHS 16
#define EPSF      1e-5f

typedef unsigned short u16;
typedef unsigned int   u32;
using short8 = __attribute__((ext_vector_type(8))) short;
using f32x4  = __attribute__((ext_vector_type(4))) float;

__device__ __forceinline__ float b2f(u16 u) {
    return __uint_as_float(((u32)u) << 16);
}
__device__ __forceinline__ u16 f2b(float f) {
    u32 u = __float_as_uint(f);
    u32 r = (u + 0x7FFFu + ((u >> 16) & 1u)) >> 16;   // RNE
    return (u16)r;
}

// ---------------- degree (weighted) + in-degree count ----------------
__global__ __launch_bounds__(256) void degcnt_kernel(const int* __restrict__ dst,
                                                     const float* __restrict__ ew,
                                                     float* __restrict__ deg,
                                                     int* __restrict__ cnt) {
    int t = blockIdx.x * blockDim.x + threadIdx.x;
    if (t < N_EDGES) {
        int d = dst[t];
        atomicAdd(&deg[d], ew[t]);
        atomicAdd(&cnt[d], 1);
    }
}

__global__ __launch_bounds__(256) void dinv_kernel(const float* __restrict__ deg,
                                                   float* __restrict__ dinv) {
    int t = blockIdx.x * blockDim.x + threadIdx.x;
    if (t < N_NODES) dinv[t] = rsqrtf(deg[t] + 1.0f);  // +1 self-loop
}

// ---------------- exclusive prefix sum over cnt -> rowptr (single block) ----
__global__ __launch_bounds__(1024) void scan_kernel(const int* __restrict__ cnt,
                                                    int* __restrict__ rowptr) {
    __shared__ int partial[1024];
    const int t = threadIdx.x;
    const int base = t * 40;
    int s = 0;
    for (int i = 0; i < 40; ++i) {
        int idx = base + i;
        if (idx < N_NODES) s += cnt[idx];
    }
    partial[t] = s;
    __syncthreads();
    for (int off = 1; off < 1024; off <<= 1) {
        int v = 0;
        if (t >= off) v = partial[t - off];
        __syncthreads();
        if (t >= off) partial[t] += v;
        __syncthreads();
    }
    int run = (t == 0) ? 0 : partial[t - 1];
    for (int i = 0; i < 40; ++i) {
        int idx = base + i;
        if (idx < N_NODES) {
            rowptr[idx] = run;
            run += cnt[idx];
        }
    }
    if (t == 0) rowptr[N_NODES] = N_EDGES;
}

// ---------------- scatter edges into CSR (by dst) ----------------
__global__ __launch_bounds__(256) void scatter_kernel(const int* __restrict__ src,
                                                      const int* __restrict__ dst,
                                                      const float* __restrict__ ew,
                                                      const float* __restrict__ dinv,
                                                      const int* __restrict__ rowptr,
                                                      int* __restrict__ cursor,
                                                      int* __restrict__ csr_src,
                                                      float* __restrict__ csr_norm) {
    int t = blockIdx.x * blockDim.x + threadIdx.x;
    if (t >= N_EDGES) return;
    int s = src[t], d = dst[t];
    int pos = rowptr[d] + atomicAdd(&cursor[d], 1);
    csr_src[pos] = s;
    csr_norm[pos] = dinv[s] * ew[t] * dinv[d];
}

// ---------------- casts / transposes ----------------
__global__ __launch_bounds__(256) void cast_x_kernel(const float* __restrict__ x,
                                                     u16* __restrict__ xb) {
    int t = blockIdx.x * blockDim.x + threadIdx.x;
    if (t < N_NODES * IN_CH) xb[t] = f2b(x[t]);
}

// W[R][C] f32 -> WT[C][R] bf16
__global__ __launch_bounds__(256) void transpose_cast_kernel(const float* __restrict__ W,
                                                             u16* __restrict__ WT,
                                                             int R, int Ccols) {
    int idx = blockIdx.x * blockDim.x + threadIdx.x;
    if (idx >= R * Ccols) return;
    int r = idx / Ccols, c = idx % Ccols;
    WT[(size_t)c * R + r] = f2b(W[idx]);
}

// ---------------- CSR aggregation, bf16 feat -> bf16 out (C=128) -----------
__global__ __launch_bounds__(256) void agg128_kernel(const int* __restrict__ rowptr,
                                                     const int* __restrict__ csr_src,
                                                     const float* __restrict__ csr_norm,
                                                     const float* __restrict__ dinv,
                                                     const u16* __restrict__ xb,
                                                     u16* __restrict__ outb) {
    const int node = (blockIdx.x * blockDim.x + threadIdx.x) >> 6;
    const int lane = threadIdx.x & 63;
    if (node >= N_NODES) return;
    const float ds = dinv[node];
    const float wself = ds * ds;
    const int e0 = rowptr[node], e1 = rowptr[node + 1];
    const int c0 = lane * 2;

    ushort2 v = *(const ushort2*)&xb[(size_t)node * IN_CH + c0];
    float ax = wself * b2f(v.x), ay = wself * b2f(v.y);
    for (int e = e0; e < e1; ++e) {
        int s = csr_src[e];
        float w = csr_norm[e];
        ushort2 u = *(const ushort2*)&xb[(size_t)s * IN_CH + c0];
        ax += w * b2f(u.x);
        ay += w * b2f(u.y);
    }
    ushort2 o = { f2b(ax), f2b(ay) };
    *(ushort2*)&outb[(size_t)node * IN_CH + c0] = o;
}

// ---------------- CSR aggregation, bf16 feat -> f32 out (C=256) ------------
__global__ __launch_bounds__(256) void agg256_kernel(const int* __restrict__ rowptr,
                                                     const int* __restrict__ csr_src,
                                                     const float* __restrict__ csr_norm,
                                                     const float* __restrict__ dinv,
                                                     const u16* __restrict__ hwb,
                                                     float* __restrict__ out) {
    const int node = (blockIdx.x * blockDim.x + threadIdx.x) >> 6;
    const int lane = threadIdx.x & 63;
    if (node >= N_NODES) return;
    const float ds = dinv[node];
    const float wself = ds * ds;
    const int e0 = rowptr[node], e1 = rowptr[node + 1];
    const int c0 = lane * 4;

    ushort4 v = *(const ushort4*)&hwb[(size_t)node * HID2 + c0];
    float4 acc = { wself * b2f(v.x), wself * b2f(v.y), wself * b2f(v.z), wself * b2f(v.w) };
    for (int e = e0; e < e1; ++e) {
        int s = csr_src[e];
        float w = csr_norm[e];
        ushort4 u = *(const ushort4*)&hwb[(size_t)s * HID2 + c0];
        acc.x += w * b2f(u.x);
        acc.y += w * b2f(u.y);
        acc.z += w * b2f(u.z);
        acc.w += w * b2f(u.w);
    }
    *(float4*)&out[(size_t)node * HID2 + c0] = acc;
}

// ---------------- MFMA GEMM: [40000,K](bf16) @ BT[N,K](bf16) ---------------
// 64x64 block tile, 4 waves (2x2), 16x16x32 MFMA, 2x2 frags per wave.
template <int K, int N, int ASTRIDE, bool BF16OUT>
__global__ __launch_bounds__(256) void mfma_gemm_kernel(const u16* __restrict__ A,
                                                        const u16* __restrict__ BT,
                                                        float* __restrict__ Cf,
                                                        u16* __restrict__ Cb) {
    __shared__ u16 As[64 * 32];
    __shared__ u16 Bs[64 * 32];
    const int t = threadIdx.x;
    const int rowbase = blockIdx.x * 64;
    const int colbase = blockIdx.y * 64;
    const int l = t & 63;
    const int wv = t >> 6;
    const int wm = (wv >> 1) * 32;       // wave row quadrant
    const int wn = (wv & 1) * 32;        // wave col quadrant
    const int fr = l & 15;               // fragment row/col index
    const int fg = l >> 4;               // k-group

    f32x4 acc[2][2];
#pragma unroll
    for (int a = 0; a < 2; ++a)
#pragma unroll
        for (int b = 0; b < 2; ++b)
            acc[a][b] = (f32x4){0.f, 0.f, 0.f, 0.f};

    const size_t arow = (size_t)(rowbase + (t >> 2)) * ASTRIDE + (t & 3) * 8;
    const size_t brow = (size_t)(colbase + (t >> 2)) * K + (t & 3) * 8;

    for (int k0 = 0; k0 < K; k0 += 32) {
        *(short8*)&As[t * 8] = *(const short8*)&A[arow + k0];
        *(short8*)&Bs[t * 8] = *(const short8*)&BT[brow + k0];
        __syncthreads();

        short8 af0 = *(const short8*)&As[(wm + fr) * 32 + fg * 8];
        short8 af1 = *(const short8*)&As[(wm + 16 + fr) * 32 + fg * 8];
        short8 bf0 = *(const short8*)&Bs[(wn + fr) * 32 + fg * 8];
        short8 bf1 = *(const short8*)&Bs[(wn + 16 + fr) * 32 + fg * 8];

        acc[0][0] = __builtin_amdgcn_mfma_f32_16x16x32_bf16(af0, bf0, acc[0][0], 0, 0, 0);
        acc[0][1] = __builtin_amdgcn_mfma_f32_16x16x32_bf16(af0, bf1, acc[0][1], 0, 0, 0);
        acc[1][0] = __builtin_amdgcn_mfma_f32_16x16x32_bf16(af1, bf0, acc[1][0], 0, 0, 0);
        acc[1][1] = __builtin_amdgcn_mfma_f32_16x16x32_bf16(af1, bf1, acc[1][1], 0, 0, 0);
        __syncthreads();
    }

#pragma unroll
    for (int fm = 0; fm < 2; ++fm)
#pragma unroll
        for (int fn = 0; fn < 2; ++fn) {
#pragma unroll
            for (int i = 0; i < 4; ++i) {
                int row = rowbase + wm + fm * 16 + fg * 4 + i;
                int col = colbase + wn + fn * 16 + fr;
                if constexpr (BF16OUT)
                    Cb[(size_t)row * N + col] = f2b(acc[fm][fn][i]);
                else
                    Cf[(size_t)row * N + col] = acc[fm][fn][i];
            }
        }
}

// ---------------- bias + ReLU + LayerNorm, C=512, f32 in -> bf16 out in place
__global__ __launch_bounds__(256) void relu_ln512_kernel(float* __restrict__ io,
                                                         const float* __restrict__ bias,
                                                         const float* __restrict__ g,
                                                         const float* __restrict__ be) {
    const int wv = (blockIdx.x * blockDim.x + threadIdx.x) >> 6;
    const int lane = threadIdx.x & 63;
    if (wv >= N_NODES) return;
    float* __restrict__ row = io + (size_t)wv * HID1;
    float v[8];
    float sum = 0.f, sq = 0.f;
#pragma unroll
    for (int j = 0; j < 8; ++j) {
        int c = lane + 64 * j;
        float x = row[c] + bias[c];
        x = fmaxf(x, 0.f);
        v[j] = x;
        sum += x;
        sq += x * x;
    }
#pragma unroll
    for (int off = 32; off >= 1; off >>= 1) {
        sum += __shfl_xor(sum, off);
        sq  += __shfl_xor(sq, off);
    }
    const float mean = sum * (1.0f / HID1);
    const float var = sq * (1.0f / HID1) - mean * mean;
    const float r = rsqrtf(var + EPSF);
    u16* __restrict__ ob = (u16*)row;   // bf16 row, stride 1024 u16 between rows
#pragma unroll
    for (int j = 0; j < 8; ++j) {
        int c = lane + 64 * j;
        ob[c] = f2b((v[j] - mean) * r * g[c] + be[c]);
    }
}

// ---------------- bias + ReLU + LayerNorm, C=256, f32 in place -------------
__global__ __launch_bounds__(256) void relu_ln256_kernel(float* __restrict__ io,
                                                         const float* __restrict__ bias,
                                                         const float* __restrict__ g,
                                                         const float* __restrict__ be) {
    const int wv = (blockIdx.x * blockDim.x + threadIdx.x) >> 6;
    const int lane = threadIdx.x & 63;
    if (wv >= N_NODES) return;
    float* __restrict__ row = io + (size_t)wv * HID2;
    float v[4];
    float sum = 0.f, sq = 0.f;
#pragma unroll
    for (int j = 0; j < 4; ++j) {
        int c = lane + 64 * j;
        float x = row[c] + bias[c];
        x = fmaxf(x, 0.f);
        v[j] = x;
        sum += x;
        sq += x * x;
    }
#pragma unroll
    for (int off = 32; off >= 1; off >>= 1) {
        sum += __shfl_xor(sum, off);
        sq  += __shfl_xor(sq, off);
    }
    const float mean = sum * (1.0f / HID2);
    const float var = sq * (1.0f / HID2) - mean * mean;
    const float r = rsqrtf(var + EPSF);
#pragma unroll
    for (int j = 0; j < 4; ++j) {
        int c = lane + 64 * j;
        row[c] = (v[j] - mean) * r * g[c] + be[c];
    }
}

// ---------------- graph boundaries (batch is sorted) ----------------
__global__ __launch_bounds__(64) void bounds_kernel(const int* __restrict__ batch,
                                                    int* __restrict__ gstart) {
    int g = threadIdx.x;
    if (g > NUM_GRAPHS) return;
    int lo = 0, hi = N_NODES;
    while (lo < hi) {
        int mid = (lo + hi) >> 1;
        if (batch[mid] < g) lo = mid + 1; else hi = mid;
    }
    gstart[g] = lo;
}

// ---------------- pool stage: per (graph, chunk) partial sums --------------
__global__ __launch_bounds__(256) void pool2_kernel(const float* __restrict__ h3,
                                                    const int* __restrict__ gstart,
                                                    float* __restrict__ pooled) {
    const int g = blockIdx.x, chunk = blockIdx.y;
    const int s = gstart[g], e = gstart[g + 1];
    const int len = e - s;
    const int c0 = s + (len * chunk) / 16;
    const int c1 = s + (len * (chunk + 1)) / 16;
    float acc = 0.f;
    for (int n = c0; n < c1; ++n)
        acc += h3[(size_t)n * HID2 + threadIdx.x];
    atomicAdd(&pooled[g * HID2 + threadIdx.x], acc);
}

// ---------------- final FC ----------------
__global__ __launch_bounds__(64) void fc_kernel(const float* __restrict__ pooled,
                                                const int* __restrict__ gstart,
                                                const float* __restrict__ Wfc,
                                                const float* __restrict__ bfc,
                                                float* __restrict__ out) {
    const int t = threadIdx.x;
    if (t >= NUM_GRAPHS * OUT_CH) return;
    const int g = t >> 1;
    const int o = t & 1;
    const int len = gstart[g + 1] - gstart[g];
    const float inv = 1.0f / fmaxf((float)len, 1.0f);
    float s = 0.f;
    for (int k = 0; k < HID2; ++k)
        s += pooled[g * HID2 + k] * Wfc[k * OUT_CH + o];
    out[t] = s * inv + bfc[o];
}

extern "C" void kernel_launch(void* const* d_in, const int* in_sizes, int n_in,
                              void* d_out, int out_size, void* d_ws, size_t ws_size,
                              hipStream_t stream) {
    const float* x   = (const float*)d_in[0];
    const int*   ei  = (const int*)d_in[1];
    const float* ew  = (const float*)d_in[2];
    const int*   bat = (const int*)d_in[3];
    const float* W1  = (const float*)d_in[4];
    const float* b1  = (const float*)d_in[5];
    const float* g1  = (const float*)d_in[6];
    const float* be1 = (const float*)d_in[7];
    const float* W2  = (const float*)d_in[8];
    const float* b2  = (const float*)d_in[9];
    const float* g2  = (const float*)d_in[10];
    const float* be2 = (const float*)d_in[11];
    const float* Wfc = (const float*)d_in[12];
    const float* bfc = (const float*)d_in[13];

    const int* srcArr = ei;
    const int* dstArr = ei + N_EDGES;

    float* out = (float*)d_out;
    float* h3  = out;                                   // [40000, 256] f32
    float* fcO = out + (size_t)N_NODES * HID2;

    // workspace layout (f32-element offsets, all 64-elem aligned)
    float* ws       = (float*)d_ws;
    float* deg      = ws;                               // 40960
    int*   cnt      = (int*)(ws + 40960);               // 40960
    int*   cursor   = (int*)(ws + 81920);               // 40960
    float* dinv     = ws + 122880;                      // 40960
    int*   rowptr   = (int*)(ws + 163840);              // 41088 (41001 used)
    int*   gstart   = (int*)(ws + 204928);              // 64 (17 used)
    int*   csr_src  = (int*)(ws + 204992);              // 640000
    float* csr_norm = ws + 844992;                      // 640000
    u16*   xb       = (u16*)(ws + 1484992);             // 40000*128 u16
    u16*   agg1b    = (u16*)(ws + 4044992);             // 40000*128 u16
    float* h_pre    = ws + 6604992;                     // 40000*512 f32 (bf16 reuses in place)
    u16*   hwb      = (u16*)(ws + 27084992);            // 40000*256 u16
    u16*   W1T      = (u16*)(ws + 32204992);            // 512*128
    u16*   W2T      = (u16*)(ws + 32237760);            // 256*512
    float* pooled   = ws + 32303296;                    // 16*256

    // 1. degree + CSR build
    hipMemsetAsync(deg, 0, 3 * 40960 * sizeof(float), stream);
    degcnt_kernel<<<(N_EDGES + 255) / 256, 256, 0, stream>>>(dstArr, ew, deg, cnt);
    dinv_kernel<<<(N_NODES + 255) / 256, 256, 0, stream>>>(deg, dinv);
    scan_kernel<<<1, 1024, 0, stream>>>(cnt, rowptr);
    scatter_kernel<<<(N_EDGES + 255) / 256, 256, 0, stream>>>(
        srcArr, dstArr, ew, dinv, rowptr, cursor, csr_src, csr_norm);

    // 2. param prep
    cast_x_kernel<<<(N_NODES * IN_CH + 255) / 256, 256, 0, stream>>>(x, xb);
    transpose_cast_kernel<<<(IN_CH * HID1 + 255) / 256, 256, 0, stream>>>(W1, W1T, IN_CH, HID1);
    transpose_cast_kernel<<<(HID1 * HID2 + 255) / 256, 256, 0, stream>>>(W2, W2T, HID1, HID2);

    // 3. layer 1: agg1 = A_norm @ x (bf16), h_pre = agg1 @ W1 (MFMA), relu+LN -> bf16
    agg128_kernel<<<(N_NODES + 3) / 4, 256, 0, stream>>>(
        rowptr, csr_src, csr_norm, dinv, xb, agg1b);
    {
        dim3 grid(N_NODES / 64, HID1 / 64);
        mfma_gemm_kernel<IN_CH, HID1, IN_CH, false><<<grid, 256, 0, stream>>>(
            agg1b, W1T, h_pre, nullptr);
    }
    relu_ln512_kernel<<<(N_NODES + 3) / 4, 256, 0, stream>>>(h_pre, b1, g1, be1);

    // 4. layer 2: hw = h @ W2 (MFMA, bf16 out), h3 = A_norm @ hw, relu+LN
    {
        dim3 grid(N_NODES / 64, HID2 / 64);
        // A = bf16 rows packed at stride 1024 u16 (in-place in h_pre)
        mfma_gemm_kernel<HID1, HID2, 1024, true><<<grid, 256, 0, stream>>>(
            (const u16*)h_pre, W2T, nullptr, hwb);
    }
    agg256_kernel<<<(N_NODES + 3) / 4, 256, 0, stream>>>(
        rowptr, csr_src, csr_norm, dinv, hwb, h3);
    relu_ln256_kernel<<<(N_NODES + 3) / 4, 256, 0, stream>>>(h3, b2, g2, be2);

    // 5. pool + fc (batch sorted -> boundary ranges, no heavy atomics)
    bounds_kernel<<<1, 64, 0, stream>>>(bat, gstart);
    hipMemsetAsync(pooled, 0, NUM_GRAPHS * HID2 * sizeof(float), stream);
    {
        dim3 grid(NUM_GRAPHS, 16);
        pool2_kernel<<<grid, 256, 0, stream>>>(h3, gstart, pooled);
    }
    fc_kernel<<<1, 64, 0, stream>>>(pooled, gstart, Wfc, bfc, fcO);
}

// Round 4
// 380.204 us; speedup vs baseline: 6.7028x; 1.2294x over previous
//
#include <hip/hip_runtime.h>
#include <hip/hip_bf16.h>

#define N_NODES   40000
#define N_EDGES   640000
#define IN_CH     128
#define HID1      512
#define HID2      256
#define OUT_CH    2
#define NUM_GRAPHS 16
#define EPSF      1e-5f

typedef unsigned short u16;
typedef unsigned int   u32;
using short8 = __attribute__((ext_vector_type(8))) short;
using f32x4  = __attribute__((ext_vector_type(4))) float;

__device__ __forceinline__ float b2f(u16 u) {
    return __uint_as_float(((u32)u) << 16);
}
__device__ __forceinline__ u16 f2b(float f) {
    u32 u = __float_as_uint(f);
    u32 r = (u + 0x7FFFu + ((u >> 16) & 1u)) >> 16;   // RNE
    return (u16)r;
}
__device__ __forceinline__ void gload_lds16(const u16* g, u16* l) {
    __builtin_amdgcn_global_load_lds((const __attribute__((address_space(1))) u32*)g,
                                     (__attribute__((address_space(3))) u32*)l, 16, 0, 0);
}

// ---------------- degree (weighted) + in-degree count ----------------
__global__ __launch_bounds__(256) void degcnt_kernel(const int* __restrict__ dst,
                                                     const float* __restrict__ ew,
                                                     float* __restrict__ deg,
                                                     int* __restrict__ cnt) {
    int t = blockIdx.x * blockDim.x + threadIdx.x;
    if (t < N_EDGES) {
        int d = dst[t];
        atomicAdd(&deg[d], ew[t]);
        atomicAdd(&cnt[d], 1);
    }
}

__global__ __launch_bounds__(256) void dinv_kernel(const float* __restrict__ deg,
                                                   float* __restrict__ dinv) {
    int t = blockIdx.x * blockDim.x + threadIdx.x;
    if (t < N_NODES) dinv[t] = rsqrtf(deg[t] + 1.0f);  // +1 self-loop
}

// ---------------- exclusive prefix sum over cnt -> rowptr (single block) ----
__global__ __launch_bounds__(1024) void scan_kernel(const int* __restrict__ cnt,
                                                    int* __restrict__ rowptr) {
    __shared__ int partial[1024];
    const int t = threadIdx.x;
    const int base = t * 40;
    int s = 0;
    for (int i = 0; i < 40; ++i) {
        int idx = base + i;
        if (idx < N_NODES) s += cnt[idx];
    }
    partial[t] = s;
    __syncthreads();
    for (int off = 1; off < 1024; off <<= 1) {
        int v = 0;
        if (t >= off) v = partial[t - off];
        __syncthreads();
        if (t >= off) partial[t] += v;
        __syncthreads();
    }
    int run = (t == 0) ? 0 : partial[t - 1];
    for (int i = 0; i < 40; ++i) {
        int idx = base + i;
        if (idx < N_NODES) {
            rowptr[idx] = run;
            run += cnt[idx];
        }
    }
    if (t == 0) rowptr[N_NODES] = N_EDGES;
}

// ---------------- scatter edges into CSR (by dst) ----------------
__global__ __launch_bounds__(256) void scatter_kernel(const int* __restrict__ src,
                                                      const int* __restrict__ dst,
                                                      const float* __restrict__ ew,
                                                      const float* __restrict__ dinv,
                                                      const int* __restrict__ rowptr,
                                                      int* __restrict__ cursor,
                                                      int* __restrict__ csr_src,
                                                      float* __restrict__ csr_norm) {
    int t = blockIdx.x * blockDim.x + threadIdx.x;
    if (t >= N_EDGES) return;
    int s = src[t], d = dst[t];
    int pos = rowptr[d] + atomicAdd(&cursor[d], 1);
    csr_src[pos] = s;
    csr_norm[pos] = dinv[s] * ew[t] * dinv[d];
}

// ---------------- casts / transposes ----------------
__global__ __launch_bounds__(256) void cast_x_kernel(const float* __restrict__ x,
                                                     u16* __restrict__ xb) {
    int t = blockIdx.x * blockDim.x + threadIdx.x;
    if (t < N_NODES * IN_CH / 4) {
        float4 v = ((const float4*)x)[t];
        ushort4 o = { f2b(v.x), f2b(v.y), f2b(v.z), f2b(v.w) };
        ((ushort4*)xb)[t] = o;
    }
}

// W[R][C] f32 -> WT[C][R] bf16
__global__ __launch_bounds__(256) void transpose_cast_kernel(const float* __restrict__ W,
                                                             u16* __restrict__ WT,
                                                             int R, int Ccols) {
    int idx = blockIdx.x * blockDim.x + threadIdx.x;
    if (idx >= R * Ccols) return;
    int r = idx / Ccols, c = idx % Ccols;
    WT[(size_t)c * R + r] = f2b(W[idx]);
}

// ---------------- CSR aggregation, bf16 -> bf16 (C=128), 4x unrolled -------
__global__ __launch_bounds__(256) void agg128_kernel(const int* __restrict__ rowptr,
                                                     const int* __restrict__ csr_src,
                                                     const float* __restrict__ csr_norm,
                                                     const float* __restrict__ dinv,
                                                     const u16* __restrict__ xb,
                                                     u16* __restrict__ outb) {
    const int node = (blockIdx.x * blockDim.x + threadIdx.x) >> 6;
    const int lane = threadIdx.x & 63;
    if (node >= N_NODES) return;
    const float ds = dinv[node];
    const float wself = ds * ds;
    const int e0 = rowptr[node], e1 = rowptr[node + 1];
    const int c0 = lane * 2;

    ushort2 v = *(const ushort2*)&xb[(size_t)node * IN_CH + c0];
    float ax = wself * b2f(v.x), ay = wself * b2f(v.y);
    int e = e0;
    for (; e + 4 <= e1; e += 4) {
        int s0 = csr_src[e], s1 = csr_src[e + 1], s2 = csr_src[e + 2], s3 = csr_src[e + 3];
        float w0 = csr_norm[e], w1 = csr_norm[e + 1], w2 = csr_norm[e + 2], w3 = csr_norm[e + 3];
        ushort2 u0 = *(const ushort2*)&xb[(size_t)s0 * IN_CH + c0];
        ushort2 u1 = *(const ushort2*)&xb[(size_t)s1 * IN_CH + c0];
        ushort2 u2 = *(const ushort2*)&xb[(size_t)s2 * IN_CH + c0];
        ushort2 u3 = *(const ushort2*)&xb[(size_t)s3 * IN_CH + c0];
        ax += w0 * b2f(u0.x) + w1 * b2f(u1.x) + w2 * b2f(u2.x) + w3 * b2f(u3.x);
        ay += w0 * b2f(u0.y) + w1 * b2f(u1.y) + w2 * b2f(u2.y) + w3 * b2f(u3.y);
    }
    for (; e < e1; ++e) {
        int s = csr_src[e];
        float w = csr_norm[e];
        ushort2 u = *(const ushort2*)&xb[(size_t)s * IN_CH + c0];
        ax += w * b2f(u.x);
        ay += w * b2f(u.y);
    }
    ushort2 o = { f2b(ax), f2b(ay) };
    *(ushort2*)&outb[(size_t)node * IN_CH + c0] = o;
}

// ------- CSR aggregation + bias + ReLU + LayerNorm (C=256), 4x unrolled ----
__global__ __launch_bounds__(256) void agg256_ln_kernel(const int* __restrict__ rowptr,
                                                        const int* __restrict__ csr_src,
                                                        const float* __restrict__ csr_norm,
                                                        const float* __restrict__ dinv,
                                                        const u16* __restrict__ hwb,
                                                        const float* __restrict__ bias,
                                                        const float* __restrict__ g,
                                                        const float* __restrict__ be,
                                                        float* __restrict__ out) {
    const int node = (blockIdx.x * blockDim.x + threadIdx.x) >> 6;
    const int lane = threadIdx.x & 63;
    if (node >= N_NODES) return;
    const float ds = dinv[node];
    const float wself = ds * ds;
    const int e0 = rowptr[node], e1 = rowptr[node + 1];
    const int c0 = lane * 4;

    ushort4 v = *(const ushort4*)&hwb[(size_t)node * HID2 + c0];
    float4 acc = { wself * b2f(v.x), wself * b2f(v.y), wself * b2f(v.z), wself * b2f(v.w) };
    int e = e0;
    for (; e + 4 <= e1; e += 4) {
        int s0 = csr_src[e], s1 = csr_src[e + 1], s2 = csr_src[e + 2], s3 = csr_src[e + 3];
        float w0 = csr_norm[e], w1 = csr_norm[e + 1], w2 = csr_norm[e + 2], w3 = csr_norm[e + 3];
        ushort4 u0 = *(const ushort4*)&hwb[(size_t)s0 * HID2 + c0];
        ushort4 u1 = *(const ushort4*)&hwb[(size_t)s1 * HID2 + c0];
        ushort4 u2 = *(const ushort4*)&hwb[(size_t)s2 * HID2 + c0];
        ushort4 u3 = *(const ushort4*)&hwb[(size_t)s3 * HID2 + c0];
        acc.x += w0 * b2f(u0.x) + w1 * b2f(u1.x) + w2 * b2f(u2.x) + w3 * b2f(u3.x);
        acc.y += w0 * b2f(u0.y) + w1 * b2f(u1.y) + w2 * b2f(u2.y) + w3 * b2f(u3.y);
        acc.z += w0 * b2f(u0.z) + w1 * b2f(u1.z) + w2 * b2f(u2.z) + w3 * b2f(u3.z);
        acc.w += w0 * b2f(u0.w) + w1 * b2f(u1.w) + w2 * b2f(u2.w) + w3 * b2f(u3.w);
    }
    for (; e < e1; ++e) {
        int s = csr_src[e];
        float w = csr_norm[e];
        ushort4 u = *(const ushort4*)&hwb[(size_t)s * HID2 + c0];
        acc.x += w * b2f(u.x);
        acc.y += w * b2f(u.y);
        acc.z += w * b2f(u.z);
        acc.w += w * b2f(u.w);
    }
    // fused bias + ReLU + LayerNorm (wave holds the full 256-ch row)
    float vv[4];
    float sum = 0.f, sq = 0.f;
#pragma unroll
    for (int j = 0; j < 4; ++j) {
        float xv = ((const float*)&acc)[j] + bias[c0 + j];
        xv = fmaxf(xv, 0.f);
        vv[j] = xv;
        sum += xv;
        sq += xv * xv;
    }
#pragma unroll
    for (int off = 32; off >= 1; off >>= 1) {
        sum += __shfl_xor(sum, off);
        sq  += __shfl_xor(sq, off);
    }
    const float mean = sum * (1.0f / HID2);
    const float var = sq * (1.0f / HID2) - mean * mean;
    const float r = rsqrtf(var + EPSF);
    float4 o;
    o.x = (vv[0] - mean) * r * g[c0 + 0] + be[c0 + 0];
    o.y = (vv[1] - mean) * r * g[c0 + 1] + be[c0 + 1];
    o.z = (vv[2] - mean) * r * g[c0 + 2] + be[c0 + 2];
    o.w = (vv[3] - mean) * r * g[c0 + 3] + be[c0 + 3];
    *(float4*)&out[(size_t)node * HID2 + c0] = o;
}

// ---------------- MFMA GEMM, 128x128 tile, 4 waves, global_load_lds --------
// A: [N_NODES, K] bf16 at row stride ASTRIDE (u16 elems); BT: [N, K] bf16.
template <int K, int N, int ASTRIDE, bool BF16OUT>
__global__ __launch_bounds__(256) void mfma_gemm128(const u16* __restrict__ A,
                                                    const u16* __restrict__ BT,
                                                    float* __restrict__ Cf,
                                                    u16* __restrict__ Cb) {
    __shared__ u16 As[128 * 32];
    __shared__ u16 Bs[128 * 32];
    const int t = threadIdx.x;
    const int rowbase = blockIdx.x * 128;
    const int colbase = blockIdx.y * 128;
    const int l = t & 63;
    const int wv = t >> 6;
    const int wm = (wv >> 1) * 64;
    const int wn = (wv & 1) * 64;
    const int fr = l & 15;
    const int fg = l >> 4;

    f32x4 acc[4][4];
#pragma unroll
    for (int a = 0; a < 4; ++a)
#pragma unroll
        for (int b = 0; b < 4; ++b)
            acc[a][b] = (f32x4){0.f, 0.f, 0.f, 0.f};

    // staging: 512 chunks of 16B per matrix; chunk c -> row c>>2, k-slot c&3.
    // wave wv owns chunks [wv*128, wv*128+128) in two issues of 64 lanes.
    const int c0i = wv * 128 + l;
    const int c1i = c0i + 64;
    int ar0 = rowbase + (c0i >> 2); if (ar0 >= N_NODES) ar0 = N_NODES - 1;
    int ar1 = rowbase + (c1i >> 2); if (ar1 >= N_NODES) ar1 = N_NODES - 1;
    const u16* ag0 = A + (size_t)ar0 * ASTRIDE + (c0i & 3) * 8;
    const u16* ag1 = A + (size_t)ar1 * ASTRIDE + (c1i & 3) * 8;
    const u16* bg0 = BT + (size_t)(colbase + (c0i >> 2)) * K + (c0i & 3) * 8;
    const u16* bg1 = BT + (size_t)(colbase + (c1i >> 2)) * K + (c1i & 3) * 8;
    u16* al0 = As + c0i * 8;
    u16* al1 = As + c1i * 8;
    u16* bl0 = Bs + c0i * 8;
    u16* bl1 = Bs + c1i * 8;

    for (int k0 = 0; k0 < K; k0 += 32) {
        gload_lds16(ag0 + k0, al0);
        gload_lds16(ag1 + k0, al1);
        gload_lds16(bg0 + k0, bl0);
        gload_lds16(bg1 + k0, bl1);
        __syncthreads();

        short8 af[4], bf[4];
#pragma unroll
        for (int fm = 0; fm < 4; ++fm)
            af[fm] = *(const short8*)&As[(wm + fm * 16 + fr) * 32 + fg * 8];
#pragma unroll
        for (int fn = 0; fn < 4; ++fn)
            bf[fn] = *(const short8*)&Bs[(wn + fn * 16 + fr) * 32 + fg * 8];
#pragma unroll
        for (int fm = 0; fm < 4; ++fm)
#pragma unroll
            for (int fn = 0; fn < 4; ++fn)
                acc[fm][fn] = __builtin_amdgcn_mfma_f32_16x16x32_bf16(af[fm], bf[fn], acc[fm][fn], 0, 0, 0);
        __syncthreads();
    }

#pragma unroll
    for (int fm = 0; fm < 4; ++fm)
#pragma unroll
        for (int fn = 0; fn < 4; ++fn) {
#pragma unroll
            for (int i = 0; i < 4; ++i) {
                int row = rowbase + wm + fm * 16 + fg * 4 + i;
                if (row < N_NODES) {
                    int col = colbase + wn + fn * 16 + fr;
                    if constexpr (BF16OUT)
                        Cb[(size_t)row * N + col] = f2b(acc[fm][fn][i]);
                    else
                        Cf[(size_t)row * N + col] = acc[fm][fn][i];
                }
            }
        }
}

// ---------------- bias + ReLU + LayerNorm, C=512, f32 in -> bf16 out in place
__global__ __launch_bounds__(256) void relu_ln512_kernel(float* __restrict__ io,
                                                         const float* __restrict__ bias,
                                                         const float* __restrict__ g,
                                                         const float* __restrict__ be) {
    const int wv = (blockIdx.x * blockDim.x + threadIdx.x) >> 6;
    const int lane = threadIdx.x & 63;
    if (wv >= N_NODES) return;
    float* __restrict__ row = io + (size_t)wv * HID1;
    float v[8];
    float sum = 0.f, sq = 0.f;
#pragma unroll
    for (int j = 0; j < 8; ++j) {
        int c = lane + 64 * j;
        float x = row[c] + bias[c];
        x = fmaxf(x, 0.f);
        v[j] = x;
        sum += x;
        sq += x * x;
    }
#pragma unroll
    for (int off = 32; off >= 1; off >>= 1) {
        sum += __shfl_xor(sum, off);
        sq  += __shfl_xor(sq, off);
    }
    const float mean = sum * (1.0f / HID1);
    const float var = sq * (1.0f / HID1) - mean * mean;
    const float r = rsqrtf(var + EPSF);
    u16* __restrict__ ob = (u16*)row;   // bf16 row, row stride 1024 u16
#pragma unroll
    for (int j = 0; j < 8; ++j) {
        int c = lane + 64 * j;
        ob[c] = f2b((v[j] - mean) * r * g[c] + be[c]);
    }
}

// ---------------- graph boundaries (batch is sorted) ----------------
__global__ __launch_bounds__(64) void bounds_kernel(const int* __restrict__ batch,
                                                    int* __restrict__ gstart) {
    int g = threadIdx.x;
    if (g > NUM_GRAPHS) return;
    int lo = 0, hi = N_NODES;
    while (lo < hi) {
        int mid = (lo + hi) >> 1;
        if (batch[mid] < g) lo = mid + 1; else hi = mid;
    }
    gstart[g] = lo;
}

// ---------------- pool stage: per (graph, chunk) partial sums --------------
__global__ __launch_bounds__(256) void pool2_kernel(const float* __restrict__ h3,
                                                    const int* __restrict__ gstart,
                                                    float* __restrict__ pooled) {
    const int g = blockIdx.x, chunk = blockIdx.y;
    const int s = gstart[g], e = gstart[g + 1];
    const int len = e - s;
    const int c0 = s + (len * chunk) / 16;
    const int c1 = s + (len * (chunk + 1)) / 16;
    float acc = 0.f;
    for (int n = c0; n < c1; ++n)
        acc += h3[(size_t)n * HID2 + threadIdx.x];
    atomicAdd(&pooled[g * HID2 + threadIdx.x], acc);
}

// ---------------- final FC ----------------
__global__ __launch_bounds__(64) void fc_kernel(const float* __restrict__ pooled,
                                                const int* __restrict__ gstart,
                                                const float* __restrict__ Wfc,
                                                const float* __restrict__ bfc,
                                                float* __restrict__ out) {
    const int t = threadIdx.x;
    if (t >= NUM_GRAPHS * OUT_CH) return;
    const int g = t >> 1;
    const int o = t & 1;
    const int len = gstart[g + 1] - gstart[g];
    const float inv = 1.0f / fmaxf((float)len, 1.0f);
    float s = 0.f;
    for (int k = 0; k < HID2; ++k)
        s += pooled[g * HID2 + k] * Wfc[k * OUT_CH + o];
    out[t] = s * inv + bfc[o];
}

extern "C" void kernel_launch(void* const* d_in, const int* in_sizes, int n_in,
                              void* d_out, int out_size, void* d_ws, size_t ws_size,
                              hipStream_t stream) {
    const float* x   = (const float*)d_in[0];
    const int*   ei  = (const int*)d_in[1];
    const float* ew  = (const float*)d_in[2];
    const int*   bat = (const int*)d_in[3];
    const float* W1  = (const float*)d_in[4];
    const float* b1  = (const float*)d_in[5];
    const float* g1  = (const float*)d_in[6];
    const float* be1 = (const float*)d_in[7];
    const float* W2  = (const float*)d_in[8];
    const float* b2  = (const float*)d_in[9];
    const float* g2  = (const float*)d_in[10];
    const float* be2 = (const float*)d_in[11];
    const float* Wfc = (const float*)d_in[12];
    const float* bfc = (const float*)d_in[13];

    const int* srcArr = ei;
    const int* dstArr = ei + N_EDGES;

    float* out = (float*)d_out;
    float* h3  = out;                                   // [40000, 256] f32
    float* fcO = out + (size_t)N_NODES * HID2;

    // workspace layout (f32-element offsets, 64-elem aligned)
    float* ws       = (float*)d_ws;
    float* deg      = ws;                               // 40960
    int*   cnt      = (int*)(ws + 40960);               // 40960
    int*   cursor   = (int*)(ws + 81920);               // 40960
    float* dinv     = ws + 122880;                      // 40960
    int*   rowptr   = (int*)(ws + 163840);              // 41088 (41001 used)
    int*   gstart   = (int*)(ws + 204928);              // 64 (17 used)
    int*   csr_src  = (int*)(ws + 204992);              // 640000
    float* csr_norm = ws + 844992;                      // 640000
    u16*   xb       = (u16*)(ws + 1484992);             // 40000*128 u16
    u16*   agg1b    = (u16*)(ws + 4044992);             // 40000*128 u16
    float* h_pre    = ws + 6604992;                     // 40000*512 f32 (bf16 in place after LN)
    u16*   hwb      = (u16*)(ws + 27084992);            // 40000*256 u16
    u16*   W1T      = (u16*)(ws + 32204992);            // 512*128 u16
    u16*   W2T      = (u16*)(ws + 32237760);            // 256*512 u16
    float* pooled   = ws + 32303296;                    // 16*256

    // 1. degree + CSR build
    hipMemsetAsync(deg, 0, 3 * 40960 * sizeof(float), stream);
    degcnt_kernel<<<(N_EDGES + 255) / 256, 256, 0, stream>>>(dstArr, ew, deg, cnt);
    dinv_kernel<<<(N_NODES + 255) / 256, 256, 0, stream>>>(deg, dinv);
    scan_kernel<<<1, 1024, 0, stream>>>(cnt, rowptr);
    scatter_kernel<<<(N_EDGES + 255) / 256, 256, 0, stream>>>(
        srcArr, dstArr, ew, dinv, rowptr, cursor, csr_src, csr_norm);

    // 2. param prep
    cast_x_kernel<<<(N_NODES * IN_CH / 4 + 255) / 256, 256, 0, stream>>>(x, xb);
    transpose_cast_kernel<<<(IN_CH * HID1 + 255) / 256, 256, 0, stream>>>(W1, W1T, IN_CH, HID1);
    transpose_cast_kernel<<<(HID1 * HID2 + 255) / 256, 256, 0, stream>>>(W2, W2T, HID1, HID2);

    // 3. layer 1: agg1 = A_norm @ x (bf16), h_pre = agg1 @ W1 (MFMA), relu+LN -> bf16
    agg128_kernel<<<(N_NODES + 3) / 4, 256, 0, stream>>>(
        rowptr, csr_src, csr_norm, dinv, xb, agg1b);
    {
        dim3 grid((N_NODES + 127) / 128, HID1 / 128);
        mfma_gemm128<IN_CH, HID1, IN_CH, false><<<grid, 256, 0, stream>>>(
            agg1b, W1T, h_pre, nullptr);
    }
    relu_ln512_kernel<<<(N_NODES + 3) / 4, 256, 0, stream>>>(h_pre, b1, g1, be1);

    // 4. layer 2: hw = h @ W2 (MFMA, bf16 out), h3 = A_norm @ hw fused with relu+LN
    {
        dim3 grid((N_NODES + 127) / 128, HID2 / 128);
        mfma_gemm128<HID1, HID2, 1024, true><<<grid, 256, 0, stream>>>(
            (const u16*)h_pre, W2T, nullptr, hwb);
    }
    agg256_ln_kernel<<<(N_NODES + 3) / 4, 256, 0, stream>>>(
        rowptr, csr_src, csr_norm, dinv, hwb, b2, g2, be2, h3);

    // 5. pool + fc
    bounds_kernel<<<1, 64, 0, stream>>>(bat, gstart);
    hipMemsetAsync(pooled, 0, NUM_GRAPHS * HID2 * sizeof(float), stream);
    {
        dim3 grid(NUM_GRAPHS, 16);
        pool2_kernel<<<grid, 256, 0, stream>>>(h3, gstart, pooled);
    }
    fc_kernel<<<1, 64, 0, stream>>>(pooled, gstart, Wfc, bfc, fcO);
}

// Round 5
// 314.862 us; speedup vs baseline: 8.0937x; 1.2075x over previous
//
#include <hip/hip_runtime.h>
#include <hip/hip_bf16.h>

#define N_NODES   40000
#define N_EDGES   640000
#define IN_CH     128
#define HID1      512
#define HID2      256
#define OUT_CH    2
#define NUM_GRAPHS 16
#define EPSF      1e-5f
#define SCAN_NB   157                 // ceil(40000/256)

typedef unsigned short u16;
typedef unsigned int   u32;
using short8 = __attribute__((ext_vector_type(8))) short;
using f32x4  = __attribute__((ext_vector_type(4))) float;

__device__ __forceinline__ float b2f(u16 u) {
    return __uint_as_float(((u32)u) << 16);
}
__device__ __forceinline__ u16 f2b(float f) {
    u32 u = __float_as_uint(f);
    u32 r = (u + 0x7FFFu + ((u >> 16) & 1u)) >> 16;   // RNE
    return (u16)r;
}
__device__ __forceinline__ void gload_lds16(const u16* g, u16* l) {
    __builtin_amdgcn_global_load_lds((const __attribute__((address_space(1))) u32*)g,
                                     (__attribute__((address_space(3))) u32*)l, 16, 0, 0);
}

// ---------------- degree (weighted) + in-degree count ----------------
__global__ __launch_bounds__(256) void degcnt_kernel(const int* __restrict__ dst,
                                                     const float* __restrict__ ew,
                                                     float* __restrict__ deg,
                                                     int* __restrict__ cnt) {
    int t = blockIdx.x * blockDim.x + threadIdx.x;
    if (t < N_EDGES) {
        int d = dst[t];
        atomicAdd(&deg[d], ew[t]);
        atomicAdd(&cnt[d], 1);
    }
}

__global__ __launch_bounds__(256) void dinv_kernel(const float* __restrict__ deg,
                                                   float* __restrict__ dinv) {
    int t = blockIdx.x * blockDim.x + threadIdx.x;
    if (t < N_NODES) dinv[t] = rsqrtf(deg[t] + 1.0f);  // +1 self-loop
}

// ---------------- 3-phase grid scan: cnt -> exclusive rowptr ----------------
__global__ __launch_bounds__(256) void scan_p1_kernel(const int* __restrict__ cnt,
                                                      int* __restrict__ rowptr,
                                                      int* __restrict__ blocksum) {
    __shared__ int sd[256];
    const int t = threadIdx.x;
    const int i = blockIdx.x * 256 + t;
    const int v = (i < N_NODES) ? cnt[i] : 0;
    sd[t] = v;
    __syncthreads();
    for (int off = 1; off < 256; off <<= 1) {
        int u = (t >= off) ? sd[t - off] : 0;
        __syncthreads();
        sd[t] += u;
        __syncthreads();
    }
    if (i < N_NODES) rowptr[i] = sd[t] - v;          // local exclusive
    if (t == 255) blocksum[blockIdx.x] = sd[255];
}

__global__ __launch_bounds__(256) void scan_p2_kernel(int* __restrict__ blocksum,
                                                      int* __restrict__ bprefix) {
    __shared__ int sd[256];
    const int t = threadIdx.x;
    const int v = (t < SCAN_NB) ? blocksum[t] : 0;
    sd[t] = v;
    __syncthreads();
    for (int off = 1; off < 256; off <<= 1) {
        int u = (t >= off) ? sd[t - off] : 0;
        __syncthreads();
        sd[t] += u;
        __syncthreads();
    }
    bprefix[t] = sd[t] - v;                          // exclusive block prefix
}

__global__ __launch_bounds__(256) void scan_p3_kernel(int* __restrict__ rowptr,
                                                      const int* __restrict__ bprefix) {
    const int i = blockIdx.x * 256 + threadIdx.x;
    if (i < N_NODES) rowptr[i] += bprefix[blockIdx.x];
    if (i == 0) rowptr[N_NODES] = N_EDGES;
}

// ---------------- scatter edges into CSR (by dst) ----------------
__global__ __launch_bounds__(256) void scatter_kernel(const int* __restrict__ src,
                                                      const int* __restrict__ dst,
                                                      const float* __restrict__ ew,
                                                      const float* __restrict__ dinv,
                                                      const int* __restrict__ rowptr,
                                                      int* __restrict__ cursor,
                                                      int* __restrict__ csr_src,
                                                      float* __restrict__ csr_norm) {
    int t = blockIdx.x * blockDim.x + threadIdx.x;
    if (t >= N_EDGES) return;
    int s = src[t], d = dst[t];
    int pos = rowptr[d] + atomicAdd(&cursor[d], 1);
    csr_src[pos] = s;
    csr_norm[pos] = dinv[s] * ew[t] * dinv[d];
}

// ---------------- casts / transposes ----------------
__global__ __launch_bounds__(256) void cast_x_kernel(const float* __restrict__ x,
                                                     u16* __restrict__ xb) {
    int t = blockIdx.x * blockDim.x + threadIdx.x;
    if (t < N_NODES * IN_CH / 4) {
        float4 v = ((const float4*)x)[t];
        ushort4 o = { f2b(v.x), f2b(v.y), f2b(v.z), f2b(v.w) };
        ((ushort4*)xb)[t] = o;
    }
}

// W[R][C] f32 -> WT[C][R] bf16
__global__ __launch_bounds__(256) void transpose_cast_kernel(const float* __restrict__ W,
                                                             u16* __restrict__ WT,
                                                             int R, int Ccols) {
    int idx = blockIdx.x * blockDim.x + threadIdx.x;
    if (idx >= R * Ccols) return;
    int r = idx / Ccols, c = idx % Ccols;
    WT[(size_t)c * R + r] = f2b(W[idx]);
}

// ---------------- CSR aggregation, bf16 -> bf16 (C=128), 4x unrolled -------
__global__ __launch_bounds__(256) void agg128_kernel(const int* __restrict__ rowptr,
                                                     const int* __restrict__ csr_src,
                                                     const float* __restrict__ csr_norm,
                                                     const float* __restrict__ dinv,
                                                     const u16* __restrict__ xb,
                                                     u16* __restrict__ outb) {
    const int node = (blockIdx.x * blockDim.x + threadIdx.x) >> 6;
    const int lane = threadIdx.x & 63;
    if (node >= N_NODES) return;
    const float ds = dinv[node];
    const float wself = ds * ds;
    const int e0 = rowptr[node], e1 = rowptr[node + 1];
    const int c0 = lane * 2;

    ushort2 v = *(const ushort2*)&xb[(size_t)node * IN_CH + c0];
    float ax = wself * b2f(v.x), ay = wself * b2f(v.y);
    int e = e0;
    for (; e + 4 <= e1; e += 4) {
        int s0 = csr_src[e], s1 = csr_src[e + 1], s2 = csr_src[e + 2], s3 = csr_src[e + 3];
        float w0 = csr_norm[e], w1 = csr_norm[e + 1], w2 = csr_norm[e + 2], w3 = csr_norm[e + 3];
        ushort2 u0 = *(const ushort2*)&xb[(size_t)s0 * IN_CH + c0];
        ushort2 u1 = *(const ushort2*)&xb[(size_t)s1 * IN_CH + c0];
        ushort2 u2 = *(const ushort2*)&xb[(size_t)s2 * IN_CH + c0];
        ushort2 u3 = *(const ushort2*)&xb[(size_t)s3 * IN_CH + c0];
        ax += w0 * b2f(u0.x) + w1 * b2f(u1.x) + w2 * b2f(u2.x) + w3 * b2f(u3.x);
        ay += w0 * b2f(u0.y) + w1 * b2f(u1.y) + w2 * b2f(u2.y) + w3 * b2f(u3.y);
    }
    for (; e < e1; ++e) {
        int s = csr_src[e];
        float w = csr_norm[e];
        ushort2 u = *(const ushort2*)&xb[(size_t)s * IN_CH + c0];
        ax += w * b2f(u.x);
        ay += w * b2f(u.y);
    }
    ushort2 o = { f2b(ax), f2b(ay) };
    *(ushort2*)&outb[(size_t)node * IN_CH + c0] = o;
}

// ------- CSR aggregation + bias + ReLU + LayerNorm (C=256), 4x unrolled ----
__global__ __launch_bounds__(256) void agg256_ln_kernel(const int* __restrict__ rowptr,
                                                        const int* __restrict__ csr_src,
                                                        const float* __restrict__ csr_norm,
                                                        const float* __restrict__ dinv,
                                                        const u16* __restrict__ hwb,
                                                        const float* __restrict__ bias,
                                                        const float* __restrict__ g,
                                                        const float* __restrict__ be,
                                                        float* __restrict__ out) {
    const int node = (blockIdx.x * blockDim.x + threadIdx.x) >> 6;
    const int lane = threadIdx.x & 63;
    if (node >= N_NODES) return;
    const float ds = dinv[node];
    const float wself = ds * ds;
    const int e0 = rowptr[node], e1 = rowptr[node + 1];
    const int c0 = lane * 4;

    ushort4 v = *(const ushort4*)&hwb[(size_t)node * HID2 + c0];
    float4 acc = { wself * b2f(v.x), wself * b2f(v.y), wself * b2f(v.z), wself * b2f(v.w) };
    int e = e0;
    for (; e + 4 <= e1; e += 4) {
        int s0 = csr_src[e], s1 = csr_src[e + 1], s2 = csr_src[e + 2], s3 = csr_src[e + 3];
        float w0 = csr_norm[e], w1 = csr_norm[e + 1], w2 = csr_norm[e + 2], w3 = csr_norm[e + 3];
        ushort4 u0 = *(const ushort4*)&hwb[(size_t)s0 * HID2 + c0];
        ushort4 u1 = *(const ushort4*)&hwb[(size_t)s1 * HID2 + c0];
        ushort4 u2 = *(const ushort4*)&hwb[(size_t)s2 * HID2 + c0];
        ushort4 u3 = *(const ushort4*)&hwb[(size_t)s3 * HID2 + c0];
        acc.x += w0 * b2f(u0.x) + w1 * b2f(u1.x) + w2 * b2f(u2.x) + w3 * b2f(u3.x);
        acc.y += w0 * b2f(u0.y) + w1 * b2f(u1.y) + w2 * b2f(u2.y) + w3 * b2f(u3.y);
        acc.z += w0 * b2f(u0.z) + w1 * b2f(u1.z) + w2 * b2f(u2.z) + w3 * b2f(u3.z);
        acc.w += w0 * b2f(u0.w) + w1 * b2f(u1.w) + w2 * b2f(u2.w) + w3 * b2f(u3.w);
    }
    for (; e < e1; ++e) {
        int s = csr_src[e];
        float w = csr_norm[e];
        ushort4 u = *(const ushort4*)&hwb[(size_t)s * HID2 + c0];
        acc.x += w * b2f(u.x);
        acc.y += w * b2f(u.y);
        acc.z += w * b2f(u.z);
        acc.w += w * b2f(u.w);
    }
    // fused bias + ReLU + LayerNorm (wave holds the full 256-ch row)
    float vv[4];
    float sum = 0.f, sq = 0.f;
#pragma unroll
    for (int j = 0; j < 4; ++j) {
        float xv = ((const float*)&acc)[j] + bias[c0 + j];
        xv = fmaxf(xv, 0.f);
        vv[j] = xv;
        sum += xv;
        sq += xv * xv;
    }
#pragma unroll
    for (int off = 32; off >= 1; off >>= 1) {
        sum += __shfl_xor(sum, off);
        sq  += __shfl_xor(sq, off);
    }
    const float mean = sum * (1.0f / HID2);
    const float var = sq * (1.0f / HID2) - mean * mean;
    const float r = rsqrtf(var + EPSF);
    float4 o;
    o.x = (vv[0] - mean) * r * g[c0 + 0] + be[c0 + 0];
    o.y = (vv[1] - mean) * r * g[c0 + 1] + be[c0 + 1];
    o.z = (vv[2] - mean) * r * g[c0 + 2] + be[c0 + 2];
    o.w = (vv[3] - mean) * r * g[c0 + 3] + be[c0 + 3];
    *(float4*)&out[(size_t)node * HID2 + c0] = o;
}

// ---------------- MFMA GEMM, 128x128 tile, 4 waves, global_load_lds --------
// A: [N_NODES, K] bf16 at row stride ASTRIDE (u16 elems); BT: [N, K] bf16.
template <int K, int N, int ASTRIDE, bool BF16OUT>
__global__ __launch_bounds__(256) void mfma_gemm128(const u16* __restrict__ A,
                                                    const u16* __restrict__ BT,
                                                    float* __restrict__ Cf,
                                                    u16* __restrict__ Cb) {
    __shared__ u16 As[128 * 32];
    __shared__ u16 Bs[128 * 32];
    const int t = threadIdx.x;
    const int rowbase = blockIdx.x * 128;
    const int colbase = blockIdx.y * 128;
    const int l = t & 63;
    const int wv = t >> 6;
    const int wm = (wv >> 1) * 64;
    const int wn = (wv & 1) * 64;
    const int fr = l & 15;
    const int fg = l >> 4;

    f32x4 acc[4][4];
#pragma unroll
    for (int a = 0; a < 4; ++a)
#pragma unroll
        for (int b = 0; b < 4; ++b)
            acc[a][b] = (f32x4){0.f, 0.f, 0.f, 0.f};

    const int c0i = wv * 128 + l;
    const int c1i = c0i + 64;
    int ar0 = rowbase + (c0i >> 2); if (ar0 >= N_NODES) ar0 = N_NODES - 1;
    int ar1 = rowbase + (c1i >> 2); if (ar1 >= N_NODES) ar1 = N_NODES - 1;
    const u16* ag0 = A + (size_t)ar0 * ASTRIDE + (c0i & 3) * 8;
    const u16* ag1 = A + (size_t)ar1 * ASTRIDE + (c1i & 3) * 8;
    const u16* bg0 = BT + (size_t)(colbase + (c0i >> 2)) * K + (c0i & 3) * 8;
    const u16* bg1 = BT + (size_t)(colbase + (c1i >> 2)) * K + (c1i & 3) * 8;
    u16* al0 = As + c0i * 8;
    u16* al1 = As + c1i * 8;
    u16* bl0 = Bs + c0i * 8;
    u16* bl1 = Bs + c1i * 8;

    for (int k0 = 0; k0 < K; k0 += 32) {
        gload_lds16(ag0 + k0, al0);
        gload_lds16(ag1 + k0, al1);
        gload_lds16(bg0 + k0, bl0);
        gload_lds16(bg1 + k0, bl1);
        __syncthreads();

        short8 af[4], bf[4];
#pragma unroll
        for (int fm = 0; fm < 4; ++fm)
            af[fm] = *(const short8*)&As[(wm + fm * 16 + fr) * 32 + fg * 8];
#pragma unroll
        for (int fn = 0; fn < 4; ++fn)
            bf[fn] = *(const short8*)&Bs[(wn + fn * 16 + fr) * 32 + fg * 8];
#pragma unroll
        for (int fm = 0; fm < 4; ++fm)
#pragma unroll
            for (int fn = 0; fn < 4; ++fn)
                acc[fm][fn] = __builtin_amdgcn_mfma_f32_16x16x32_bf16(af[fm], bf[fn], acc[fm][fn], 0, 0, 0);
        __syncthreads();
    }

#pragma unroll
    for (int fm = 0; fm < 4; ++fm)
#pragma unroll
        for (int fn = 0; fn < 4; ++fn) {
#pragma unroll
            for (int i = 0; i < 4; ++i) {
                int row = rowbase + wm + fm * 16 + fg * 4 + i;
                if (row < N_NODES) {
                    int col = colbase + wn + fn * 16 + fr;
                    if constexpr (BF16OUT)
                        Cb[(size_t)row * N + col] = f2b(acc[fm][fn][i]);
                    else
                        Cf[(size_t)row * N + col] = acc[fm][fn][i];
                }
            }
        }
}

// ---------------- bias + ReLU + LayerNorm, C=512, f32 in -> bf16 out in place
__global__ __launch_bounds__(256) void relu_ln512_kernel(float* __restrict__ io,
                                                         const float* __restrict__ bias,
                                                         const float* __restrict__ g,
                                                         const float* __restrict__ be) {
    const int wv = (blockIdx.x * blockDim.x + threadIdx.x) >> 6;
    const int lane = threadIdx.x & 63;
    if (wv >= N_NODES) return;
    float* __restrict__ row = io + (size_t)wv * HID1;
    float v[8];
    float sum = 0.f, sq = 0.f;
#pragma unroll
    for (int j = 0; j < 8; ++j) {
        int c = lane + 64 * j;
        float x = row[c] + bias[c];
        x = fmaxf(x, 0.f);
        v[j] = x;
        sum += x;
        sq += x * x;
    }
#pragma unroll
    for (int off = 32; off >= 1; off >>= 1) {
        sum += __shfl_xor(sum, off);
        sq  += __shfl_xor(sq, off);
    }
    const float mean = sum * (1.0f / HID1);
    const float var = sq * (1.0f / HID1) - mean * mean;
    const float r = rsqrtf(var + EPSF);
    u16* __restrict__ ob = (u16*)row;   // bf16 row, row stride 1024 u16
#pragma unroll
    for (int j = 0; j < 8; ++j) {
        int c = lane + 64 * j;
        ob[c] = f2b((v[j] - mean) * r * g[c] + be[c]);
    }
}

// ---------------- graph boundaries (batch is sorted) ----------------
__global__ __launch_bounds__(64) void bounds_kernel(const int* __restrict__ batch,
                                                    int* __restrict__ gstart) {
    int g = threadIdx.x;
    if (g > NUM_GRAPHS) return;
    int lo = 0, hi = N_NODES;
    while (lo < hi) {
        int mid = (lo + hi) >> 1;
        if (batch[mid] < g) lo = mid + 1; else hi = mid;
    }
    gstart[g] = lo;
}

// ---------------- pool stage: per (graph, chunk) partial sums --------------
__global__ __launch_bounds__(256) void pool2_kernel(const float* __restrict__ h3,
                                                    const int* __restrict__ gstart,
                                                    float* __restrict__ pooled) {
    const int g = blockIdx.x, chunk = blockIdx.y;
    const int s = gstart[g], e = gstart[g + 1];
    const int len = e - s;
    const int c0 = s + (len * chunk) / 16;
    const int c1 = s + (len * (chunk + 1)) / 16;
    float acc = 0.f;
    for (int n = c0; n < c1; ++n)
        acc += h3[(size_t)n * HID2 + threadIdx.x];
    atomicAdd(&pooled[g * HID2 + threadIdx.x], acc);
}

// ---------------- final FC ----------------
__global__ __launch_bounds__(64) void fc_kernel(const float* __restrict__ pooled,
                                                const int* __restrict__ gstart,
                                                const float* __restrict__ Wfc,
                                                const float* __restrict__ bfc,
                                                float* __restrict__ out) {
    const int t = threadIdx.x;
    if (t >= NUM_GRAPHS * OUT_CH) return;
    const int g = t >> 1;
    const int o = t & 1;
    const int len = gstart[g + 1] - gstart[g];
    const float inv = 1.0f / fmaxf((float)len, 1.0f);
    float s = 0.f;
    for (int k = 0; k < HID2; ++k)
        s += pooled[g * HID2 + k] * Wfc[k * OUT_CH + o];
    out[t] = s * inv + bfc[o];
}

extern "C" void kernel_launch(void* const* d_in, const int* in_sizes, int n_in,
                              void* d_out, int out_size, void* d_ws, size_t ws_size,
                              hipStream_t stream) {
    const float* x   = (const float*)d_in[0];
    const int*   ei  = (const int*)d_in[1];
    const float* ew  = (const float*)d_in[2];
    const int*   bat = (const int*)d_in[3];
    const float* W1  = (const float*)d_in[4];
    const float* b1  = (const float*)d_in[5];
    const float* g1  = (const float*)d_in[6];
    const float* be1 = (const float*)d_in[7];
    const float* W2  = (const float*)d_in[8];
    const float* b2  = (const float*)d_in[9];
    const float* g2  = (const float*)d_in[10];
    const float* be2 = (const float*)d_in[11];
    const float* Wfc = (const float*)d_in[12];
    const float* bfc = (const float*)d_in[13];

    const int* srcArr = ei;
    const int* dstArr = ei + N_EDGES;

    float* out = (float*)d_out;
    float* h3  = out;                                   // [40000, 256] f32
    float* fcO = out + (size_t)N_NODES * HID2;

    // workspace layout (f32-element offsets, 64-elem aligned)
    float* ws       = (float*)d_ws;
    float* deg      = ws;                               // 40960
    int*   cnt      = (int*)(ws + 40960);               // 40960
    int*   cursor   = (int*)(ws + 81920);               // 40960
    float* dinv     = ws + 122880;                      // 40960
    int*   rowptr   = (int*)(ws + 163840);              // 41088 (41001 used)
    int*   gstart   = (int*)(ws + 204928);              // 64 (17 used)
    int*   blocksum = (int*)(ws + 204992);              // 256
    int*   bprefix  = (int*)(ws + 205248);              // 256
    int*   csr_src  = (int*)(ws + 205504);              // 640000
    float* csr_norm = ws + 845504;                      // 640000
    u16*   xb       = (u16*)(ws + 1485504);             // 40000*128 u16
    u16*   agg1b    = (u16*)(ws + 4045504);             // 40000*128 u16
    float* h_pre    = ws + 6605504;                     // 40000*512 f32 (bf16 in place after LN)
    u16*   hwb      = (u16*)(ws + 27085504);            // 40000*256 u16
    u16*   W1T      = (u16*)(ws + 32205504);            // 512*128 u16
    u16*   W2T      = (u16*)(ws + 32238272);            // 256*512 u16
    float* pooled   = ws + 32303808;                    // 16*256

    // 1. degree + CSR build
    hipMemsetAsync(deg, 0, 3 * 40960 * sizeof(float), stream);
    degcnt_kernel<<<(N_EDGES + 255) / 256, 256, 0, stream>>>(dstArr, ew, deg, cnt);
    dinv_kernel<<<(N_NODES + 255) / 256, 256, 0, stream>>>(deg, dinv);
    scan_p1_kernel<<<SCAN_NB, 256, 0, stream>>>(cnt, rowptr, blocksum);
    scan_p2_kernel<<<1, 256, 0, stream>>>(blocksum, bprefix);
    scan_p3_kernel<<<SCAN_NB, 256, 0, stream>>>(rowptr, bprefix);
    scatter_kernel<<<(N_EDGES + 255) / 256, 256, 0, stream>>>(
        srcArr, dstArr, ew, dinv, rowptr, cursor, csr_src, csr_norm);

    // 2. param prep
    cast_x_kernel<<<(N_NODES * IN_CH / 4 + 255) / 256, 256, 0, stream>>>(x, xb);
    transpose_cast_kernel<<<(IN_CH * HID1 + 255) / 256, 256, 0, stream>>>(W1, W1T, IN_CH, HID1);
    transpose_cast_kernel<<<(HID1 * HID2 + 255) / 256, 256, 0, stream>>>(W2, W2T, HID1, HID2);

    // 3. layer 1: agg1 = A_norm @ x (bf16), h_pre = agg1 @ W1 (MFMA), relu+LN -> bf16
    agg128_kernel<<<(N_NODES + 3) / 4, 256, 0, stream>>>(
        rowptr, csr_src, csr_norm, dinv, xb, agg1b);
    {
        dim3 grid((N_NODES + 127) / 128, HID1 / 128);
        mfma_gemm128<IN_CH, HID1, IN_CH, false><<<grid, 256, 0, stream>>>(
            agg1b, W1T, h_pre, nullptr);
    }
    relu_ln512_kernel<<<(N_NODES + 3) / 4, 256, 0, stream>>>(h_pre, b1, g1, be1);

    // 4. layer 2: hw = h @ W2 (MFMA, bf16 out), h3 = A_norm @ hw fused with relu+LN
    {
        dim3 grid((N_NODES + 127) / 128, HID2 / 128);
        mfma_gemm128<HID1, HID2, 1024, true><<<grid, 256, 0, stream>>>(
            (const u16*)h_pre, W2T, nullptr, hwb);
    }
    agg256_ln_kernel<<<(N_NODES + 3) / 4, 256, 0, stream>>>(
        rowptr, csr_src, csr_norm, dinv, hwb, b2, g2, be2, h3);

    // 5. pool + fc
    bounds_kernel<<<1, 64, 0, stream>>>(bat, gstart);
    hipMemsetAsync(pooled, 0, NUM_GRAPHS * HID2 * sizeof(float), stream);
    {
        dim3 grid(NUM_GRAPHS, 16);
        pool2_kernel<<<grid, 256, 0, stream>>>(h3, gstart, pooled);
    }
    fc_kernel<<<1, 64, 0, stream>>>(pooled, gstart, Wfc, bfc, fcO);
}

// Round 6
// 270.701 us; speedup vs baseline: 9.4141x; 1.1631x over previous
//
#include <hip/hip_runtime.h>
#include <hip/hip_bf16.h>

#define N_NODES   40000
#define N_EDGES   640000
#define IN_CH     128
#define HID1      512
#define HID2      256
#define OUT_CH    2
#define NUM_GRAPHS 16
#define EPSF      1e-5f
#define SCAN_NB   157                 // ceil(40000/256)
#define FIXSC     1048576.0f          // 2^20 fixed-point scale for edge weights

typedef unsigned short u16;
typedef unsigned int   u32;
typedef unsigned long long u64;
using short8 = __attribute__((ext_vector_type(8))) short;
using f32x4  = __attribute__((ext_vector_type(4))) float;

__device__ __forceinline__ float b2f(u16 u) {
    return __uint_as_float(((u32)u) << 16);
}
__device__ __forceinline__ u16 f2b(float f) {
    u32 u = __float_as_uint(f);
    u32 r = (u + 0x7FFFu + ((u >> 16) & 1u)) >> 16;   // RNE
    return (u16)r;
}
__device__ __forceinline__ void gload_lds16(const u16* g, u16* l) {
    __builtin_amdgcn_global_load_lds((const __attribute__((address_space(1))) u32*)g,
                                     (__attribute__((address_space(3))) u32*)l, 16, 0, 0);
}

// ------- pass 1: one u64 atomic per edge: cnt(high24) | fix20(ew) (low40) ---
// old>>40 = this edge's slot within its dst row.
__global__ __launch_bounds__(256) void pack_kernel(const int* __restrict__ dst,
                                                   const float* __restrict__ ew,
                                                   u64* __restrict__ packed,
                                                   int* __restrict__ eoff) {
    int t = blockIdx.x * blockDim.x + threadIdx.x;
    if (t >= N_EDGES) return;
    int d = dst[t];
    u64 inc = (1ull << 40) | (u64)__float2uint_rn(ew[t] * FIXSC);
    u64 old = atomicAdd(&packed[d], inc);
    eoff[t] = (int)(old >> 40);
}

// ---- scan phase 1 (fused unpack): packed -> dinv, local-excl rowptr, blocksum
__global__ __launch_bounds__(256) void scan_p1_kernel(const u64* __restrict__ packed,
                                                      float* __restrict__ dinv,
                                                      int* __restrict__ rowptr,
                                                      int* __restrict__ blocksum) {
    __shared__ int sd[256];
    const int t = threadIdx.x;
    const int i = blockIdx.x * 256 + t;
    int v = 0;
    if (i < N_NODES) {
        u64 p = packed[i];
        v = (int)(p >> 40);
        float deg = (float)(p & ((1ull << 40) - 1)) * (1.0f / FIXSC);
        dinv[i] = rsqrtf(deg + 1.0f);              // +1 self-loop
    }
    sd[t] = v;
    __syncthreads();
    for (int off = 1; off < 256; off <<= 1) {
        int u = (t >= off) ? sd[t - off] : 0;
        __syncthreads();
        sd[t] += u;
        __syncthreads();
    }
    if (i < N_NODES) rowptr[i] = sd[t] - v;        // local exclusive
    if (t == 255) blocksum[blockIdx.x] = sd[255];
}

__global__ __launch_bounds__(256) void scan_p2_kernel(int* __restrict__ blocksum,
                                                      int* __restrict__ bprefix) {
    __shared__ int sd[256];
    const int t = threadIdx.x;
    const int v = (t < SCAN_NB) ? blocksum[t] : 0;
    sd[t] = v;
    __syncthreads();
    for (int off = 1; off < 256; off <<= 1) {
        int u = (t >= off) ? sd[t - off] : 0;
        __syncthreads();
        sd[t] += u;
        __syncthreads();
    }
    bprefix[t] = sd[t] - v;                        // exclusive block prefix
}

__global__ __launch_bounds__(256) void scan_p3_kernel(int* __restrict__ rowptr,
                                                      const int* __restrict__ bprefix) {
    const int i = blockIdx.x * 256 + threadIdx.x;
    if (i < N_NODES) rowptr[i] += bprefix[blockIdx.x];
    if (i == 0) rowptr[N_NODES] = N_EDGES;
}

// ---------------- scatter edges into CSR (atomic-free) ----------------
__global__ __launch_bounds__(256) void scatter_kernel(const int* __restrict__ src,
                                                      const int* __restrict__ dst,
                                                      const float* __restrict__ ew,
                                                      const float* __restrict__ dinv,
                                                      const int* __restrict__ rowptr,
                                                      const int* __restrict__ eoff,
                                                      int* __restrict__ csr_src,
                                                      float* __restrict__ csr_norm) {
    int t = blockIdx.x * blockDim.x + threadIdx.x;
    if (t >= N_EDGES) return;
    int s = src[t], d = dst[t];
    int pos = rowptr[d] + eoff[t];
    csr_src[pos] = s;
    csr_norm[pos] = dinv[s] * ew[t] * dinv[d];
}

// ---------------- casts / transposes ----------------
__global__ __launch_bounds__(256) void cast_x_kernel(const float* __restrict__ x,
                                                     u16* __restrict__ xb) {
    int t = blockIdx.x * blockDim.x + threadIdx.x;
    if (t < N_NODES * IN_CH / 4) {
        float4 v = ((const float4*)x)[t];
        ushort4 o = { f2b(v.x), f2b(v.y), f2b(v.z), f2b(v.w) };
        ((ushort4*)xb)[t] = o;
    }
}

// W[R][C] f32 -> WT[C][R] bf16
__global__ __launch_bounds__(256) void transpose_cast_kernel(const float* __restrict__ W,
                                                             u16* __restrict__ WT,
                                                             int R, int Ccols) {
    int idx = blockIdx.x * blockDim.x + threadIdx.x;
    if (idx >= R * Ccols) return;
    int r = idx / Ccols, c = idx % Ccols;
    WT[(size_t)c * R + r] = f2b(W[idx]);
}

// ---------------- CSR aggregation, bf16 -> bf16 (C=128), 8x unrolled -------
__global__ __launch_bounds__(256) void agg128_kernel(const int* __restrict__ rowptr,
                                                     const int* __restrict__ csr_src,
                                                     const float* __restrict__ csr_norm,
                                                     const float* __restrict__ dinv,
                                                     const u16* __restrict__ xb,
                                                     u16* __restrict__ outb) {
    const int node = (blockIdx.x * blockDim.x + threadIdx.x) >> 6;
    const int lane = threadIdx.x & 63;
    if (node >= N_NODES) return;
    const float ds = dinv[node];
    const float wself = ds * ds;
    const int e0 = rowptr[node], e1 = rowptr[node + 1];
    const int c0 = lane * 2;

    ushort2 v = *(const ushort2*)&xb[(size_t)node * IN_CH + c0];
    float ax = wself * b2f(v.x), ay = wself * b2f(v.y);
    int e = e0;
    for (; e + 8 <= e1; e += 8) {
        int   si[8]; float wi[8]; ushort2 ui[8];
#pragma unroll
        for (int j = 0; j < 8; ++j) { si[j] = csr_src[e + j]; wi[j] = csr_norm[e + j]; }
#pragma unroll
        for (int j = 0; j < 8; ++j) ui[j] = *(const ushort2*)&xb[(size_t)si[j] * IN_CH + c0];
#pragma unroll
        for (int j = 0; j < 8; ++j) {
            ax += wi[j] * b2f(ui[j].x);
            ay += wi[j] * b2f(ui[j].y);
        }
    }
    for (; e < e1; ++e) {
        int s = csr_src[e];
        float w = csr_norm[e];
        ushort2 u = *(const ushort2*)&xb[(size_t)s * IN_CH + c0];
        ax += w * b2f(u.x);
        ay += w * b2f(u.y);
    }
    ushort2 o = { f2b(ax), f2b(ay) };
    *(ushort2*)&outb[(size_t)node * IN_CH + c0] = o;
}

// ------- CSR aggregation + bias + ReLU + LayerNorm (C=256), 8x unrolled ----
__global__ __launch_bounds__(256) void agg256_ln_kernel(const int* __restrict__ rowptr,
                                                        const int* __restrict__ csr_src,
                                                        const float* __restrict__ csr_norm,
                                                        const float* __restrict__ dinv,
                                                        const u16* __restrict__ hwb,
                                                        const float* __restrict__ bias,
                                                        const float* __restrict__ g,
                                                        const float* __restrict__ be,
                                                        float* __restrict__ out) {
    const int node = (blockIdx.x * blockDim.x + threadIdx.x) >> 6;
    const int lane = threadIdx.x & 63;
    if (node >= N_NODES) return;
    const float ds = dinv[node];
    const float wself = ds * ds;
    const int e0 = rowptr[node], e1 = rowptr[node + 1];
    const int c0 = lane * 4;

    ushort4 v = *(const ushort4*)&hwb[(size_t)node * HID2 + c0];
    float4 acc = { wself * b2f(v.x), wself * b2f(v.y), wself * b2f(v.z), wself * b2f(v.w) };
    int e = e0;
    for (; e + 8 <= e1; e += 8) {
        int si[8]; float wi[8]; ushort4 ui[8];
#pragma unroll
        for (int j = 0; j < 8; ++j) { si[j] = csr_src[e + j]; wi[j] = csr_norm[e + j]; }
#pragma unroll
        for (int j = 0; j < 8; ++j) ui[j] = *(const ushort4*)&hwb[(size_t)si[j] * HID2 + c0];
#pragma unroll
        for (int j = 0; j < 8; ++j) {
            acc.x += wi[j] * b2f(ui[j].x);
            acc.y += wi[j] * b2f(ui[j].y);
            acc.z += wi[j] * b2f(ui[j].z);
            acc.w += wi[j] * b2f(ui[j].w);
        }
    }
    for (; e < e1; ++e) {
        int s = csr_src[e];
        float w = csr_norm[e];
        ushort4 u = *(const ushort4*)&hwb[(size_t)s * HID2 + c0];
        acc.x += w * b2f(u.x);
        acc.y += w * b2f(u.y);
        acc.z += w * b2f(u.z);
        acc.w += w * b2f(u.w);
    }
    // fused bias + ReLU + LayerNorm
    float vv[4];
    float sum = 0.f, sq = 0.f;
#pragma unroll
    for (int j = 0; j < 4; ++j) {
        float xv = ((const float*)&acc)[j] + bias[c0 + j];
        xv = fmaxf(xv, 0.f);
        vv[j] = xv;
        sum += xv;
        sq += xv * xv;
    }
#pragma unroll
    for (int off = 32; off >= 1; off >>= 1) {
        sum += __shfl_xor(sum, off);
        sq  += __shfl_xor(sq, off);
    }
    const float mean = sum * (1.0f / HID2);
    const float var = sq * (1.0f / HID2) - mean * mean;
    const float r = rsqrtf(var + EPSF);
    float4 o;
    o.x = (vv[0] - mean) * r * g[c0 + 0] + be[c0 + 0];
    o.y = (vv[1] - mean) * r * g[c0 + 1] + be[c0 + 1];
    o.z = (vv[2] - mean) * r * g[c0 + 2] + be[c0 + 2];
    o.w = (vv[3] - mean) * r * g[c0 + 3] + be[c0 + 3];
    *(float4*)&out[(size_t)node * HID2 + c0] = o;
}

// ---------------- MFMA GEMM, 128x128 tile, 4 waves, global_load_lds --------
// A: [N_NODES, K] bf16 row stride ASTRIDE (u16); BT: [N, K] bf16. bf16 out.
template <int K, int N, int ASTRIDE>
__global__ __launch_bounds__(256) void mfma_gemm128(const u16* __restrict__ A,
                                                    const u16* __restrict__ BT,
                                                    u16* __restrict__ Cb) {
    __shared__ u16 As[128 * 32];
    __shared__ u16 Bs[128 * 32];
    const int t = threadIdx.x;
    const int rowbase = blockIdx.x * 128;
    const int colbase = blockIdx.y * 128;
    const int l = t & 63;
    const int wv = t >> 6;
    const int wm = (wv >> 1) * 64;
    const int wn = (wv & 1) * 64;
    const int fr = l & 15;
    const int fg = l >> 4;

    f32x4 acc[4][4];
#pragma unroll
    for (int a = 0; a < 4; ++a)
#pragma unroll
        for (int b = 0; b < 4; ++b)
            acc[a][b] = (f32x4){0.f, 0.f, 0.f, 0.f};

    const int c0i = wv * 128 + l;
    const int c1i = c0i + 64;
    int ar0 = rowbase + (c0i >> 2); if (ar0 >= N_NODES) ar0 = N_NODES - 1;
    int ar1 = rowbase + (c1i >> 2); if (ar1 >= N_NODES) ar1 = N_NODES - 1;
    const u16* ag0 = A + (size_t)ar0 * ASTRIDE + (c0i & 3) * 8;
    const u16* ag1 = A + (size_t)ar1 * ASTRIDE + (c1i & 3) * 8;
    const u16* bg0 = BT + (size_t)(colbase + (c0i >> 2)) * K + (c0i & 3) * 8;
    const u16* bg1 = BT + (size_t)(colbase + (c1i >> 2)) * K + (c1i & 3) * 8;
    u16* al0 = As + c0i * 8;
    u16* al1 = As + c1i * 8;
    u16* bl0 = Bs + c0i * 8;
    u16* bl1 = Bs + c1i * 8;

    for (int k0 = 0; k0 < K; k0 += 32) {
        gload_lds16(ag0 + k0, al0);
        gload_lds16(ag1 + k0, al1);
        gload_lds16(bg0 + k0, bl0);
        gload_lds16(bg1 + k0, bl1);
        __syncthreads();

        short8 af[4], bf[4];
#pragma unroll
        for (int fm = 0; fm < 4; ++fm)
            af[fm] = *(const short8*)&As[(wm + fm * 16 + fr) * 32 + fg * 8];
#pragma unroll
        for (int fn = 0; fn < 4; ++fn)
            bf[fn] = *(const short8*)&Bs[(wn + fn * 16 + fr) * 32 + fg * 8];
#pragma unroll
        for (int fm = 0; fm < 4; ++fm)
#pragma unroll
            for (int fn = 0; fn < 4; ++fn)
                acc[fm][fn] = __builtin_amdgcn_mfma_f32_16x16x32_bf16(af[fm], bf[fn], acc[fm][fn], 0, 0, 0);
        __syncthreads();
    }

#pragma unroll
    for (int fm = 0; fm < 4; ++fm)
#pragma unroll
        for (int fn = 0; fn < 4; ++fn) {
#pragma unroll
            for (int i = 0; i < 4; ++i) {
                int row = rowbase + wm + fm * 16 + fg * 4 + i;
                if (row < N_NODES) {
                    int col = colbase + wn + fn * 16 + fr;
                    Cb[(size_t)row * N + col] = f2b(acc[fm][fn][i]);
                }
            }
        }
}

// ------- bias + ReLU + LayerNorm, C=512, bf16 in/out, dense, vectorized ----
__global__ __launch_bounds__(256) void relu_ln512b_kernel(u16* __restrict__ io,
                                                          const float* __restrict__ bias,
                                                          const float* __restrict__ g,
                                                          const float* __restrict__ be) {
    const int wv = (blockIdx.x * blockDim.x + threadIdx.x) >> 6;
    const int lane = threadIdx.x & 63;
    if (wv >= N_NODES) return;
    u16* __restrict__ row = io + (size_t)wv * HID1;
    const int c0 = lane * 8;
    short8 raw = *(const short8*)&row[c0];
    float v[8];
    float sum = 0.f, sq = 0.f;
#pragma unroll
    for (int j = 0; j < 8; ++j) {
        float xv = b2f((u16)raw[j]) + bias[c0 + j];
        xv = fmaxf(xv, 0.f);
        v[j] = xv;
        sum += xv;
        sq += xv * xv;
    }
#pragma unroll
    for (int off = 32; off >= 1; off >>= 1) {
        sum += __shfl_xor(sum, off);
        sq  += __shfl_xor(sq, off);
    }
    const float mean = sum * (1.0f / HID1);
    const float var = sq * (1.0f / HID1) - mean * mean;
    const float r = rsqrtf(var + EPSF);
    short8 o;
#pragma unroll
    for (int j = 0; j < 8; ++j)
        o[j] = (short)f2b((v[j] - mean) * r * g[c0 + j] + be[c0 + j]);
    *(short8*)&row[c0] = o;
}

// ---------------- graph boundaries (batch is sorted) ----------------
__global__ __launch_bounds__(64) void bounds_kernel(const int* __restrict__ batch,
                                                    int* __restrict__ gstart) {
    int g = threadIdx.x;
    if (g > NUM_GRAPHS) return;
    int lo = 0, hi = N_NODES;
    while (lo < hi) {
        int mid = (lo + hi) >> 1;
        if (batch[mid] < g) lo = mid + 1; else hi = mid;
    }
    gstart[g] = lo;
}

// ---------------- pool stage: per (graph, chunk) partial sums --------------
__global__ __launch_bounds__(256) void pool2_kernel(const float* __restrict__ h3,
                                                    const int* __restrict__ gstart,
                                                    float* __restrict__ pooled) {
    const int g = blockIdx.x, chunk = blockIdx.y;
    const int s = gstart[g], e = gstart[g + 1];
    const int len = e - s;
    const int c0 = s + (len * chunk) / 16;
    const int c1 = s + (len * (chunk + 1)) / 16;
    float acc = 0.f;
    for (int n = c0; n < c1; ++n)
        acc += h3[(size_t)n * HID2 + threadIdx.x];
    atomicAdd(&pooled[g * HID2 + threadIdx.x], acc);
}

// ---------------- final FC ----------------
__global__ __launch_bounds__(64) void fc_kernel(const float* __restrict__ pooled,
                                                const int* __restrict__ gstart,
                                                const float* __restrict__ Wfc,
                                                const float* __restrict__ bfc,
                                                float* __restrict__ out) {
    const int t = threadIdx.x;
    if (t >= NUM_GRAPHS * OUT_CH) return;
    const int g = t >> 1;
    const int o = t & 1;
    const int len = gstart[g + 1] - gstart[g];
    const float inv = 1.0f / fmaxf((float)len, 1.0f);
    float s = 0.f;
    for (int k = 0; k < HID2; ++k)
        s += pooled[g * HID2 + k] * Wfc[k * OUT_CH + o];
    out[t] = s * inv + bfc[o];
}

extern "C" void kernel_launch(void* const* d_in, const int* in_sizes, int n_in,
                              void* d_out, int out_size, void* d_ws, size_t ws_size,
                              hipStream_t stream) {
    const float* x   = (const float*)d_in[0];
    const int*   ei  = (const int*)d_in[1];
    const float* ew  = (const float*)d_in[2];
    const int*   bat = (const int*)d_in[3];
    const float* W1  = (const float*)d_in[4];
    const float* b1  = (const float*)d_in[5];
    const float* g1  = (const float*)d_in[6];
    const float* be1 = (const float*)d_in[7];
    const float* W2  = (const float*)d_in[8];
    const float* b2  = (const float*)d_in[9];
    const float* g2  = (const float*)d_in[10];
    const float* be2 = (const float*)d_in[11];
    const float* Wfc = (const float*)d_in[12];
    const float* bfc = (const float*)d_in[13];

    const int* srcArr = ei;
    const int* dstArr = ei + N_EDGES;

    float* out = (float*)d_out;
    float* h3  = out;                                   // [40000, 256] f32
    float* fcO = out + (size_t)N_NODES * HID2;

    // workspace layout (f32-element offsets; packed is 8B-aligned at base)
    float* ws       = (float*)d_ws;
    u64*   packed   = (u64*)ws;                         // 40960 u64  (81920 f32)
    float* dinv     = ws + 81920;                       // 40960
    int*   rowptr   = (int*)(ws + 122880);              // 41088 (41001 used)
    int*   gstart   = (int*)(ws + 163968);              // 64
    int*   blocksum = (int*)(ws + 164032);              // 256
    int*   bprefix  = (int*)(ws + 164288);              // 256
    int*   eoff     = (int*)(ws + 164544);              // 640000
    int*   csr_src  = (int*)(ws + 804544);              // 640000
    float* csr_norm = ws + 1444544;                     // 640000
    u16*   xb       = (u16*)(ws + 2084544);             // 40000*128 u16
    u16*   agg1b    = (u16*)(ws + 4644544);             // 40000*128 u16
    u16*   hb       = (u16*)(ws + 7204544);             // 40000*512 u16 (dense bf16 h)
    u16*   hwb      = (u16*)(ws + 17444544);            // 40000*256 u16
    u16*   W1T      = (u16*)(ws + 22564544);            // 512*128 u16
    u16*   W2T      = (u16*)(ws + 22597312);            // 256*512 u16
    float* pooled   = ws + 22662848;                    // 16*256

    // 1. degree/count/slot in ONE atomic pass + CSR build (atomic-free scatter)
    hipMemsetAsync(packed, 0, 40960 * sizeof(u64), stream);
    pack_kernel<<<(N_EDGES + 255) / 256, 256, 0, stream>>>(dstArr, ew, packed, eoff);
    scan_p1_kernel<<<SCAN_NB, 256, 0, stream>>>(packed, dinv, rowptr, blocksum);
    scan_p2_kernel<<<1, 256, 0, stream>>>(blocksum, bprefix);
    scan_p3_kernel<<<SCAN_NB, 256, 0, stream>>>(rowptr, bprefix);
    scatter_kernel<<<(N_EDGES + 255) / 256, 256, 0, stream>>>(
        srcArr, dstArr, ew, dinv, rowptr, eoff, csr_src, csr_norm);

    // 2. param prep
    cast_x_kernel<<<(N_NODES * IN_CH / 4 + 255) / 256, 256, 0, stream>>>(x, xb);
    transpose_cast_kernel<<<(IN_CH * HID1 + 255) / 256, 256, 0, stream>>>(W1, W1T, IN_CH, HID1);
    transpose_cast_kernel<<<(HID1 * HID2 + 255) / 256, 256, 0, stream>>>(W2, W2T, HID1, HID2);

    // 3. layer 1: agg1 = A_norm @ x (bf16), h = agg1 @ W1 (MFMA -> bf16), relu+LN bf16
    agg128_kernel<<<(N_NODES + 3) / 4, 256, 0, stream>>>(
        rowptr, csr_src, csr_norm, dinv, xb, agg1b);
    {
        dim3 grid((N_NODES + 127) / 128, HID1 / 128);
        mfma_gemm128<IN_CH, HID1, IN_CH><<<grid, 256, 0, stream>>>(agg1b, W1T, hb);
    }
    relu_ln512b_kernel<<<(N_NODES + 3) / 4, 256, 0, stream>>>(hb, b1, g1, be1);

    // 4. layer 2: hw = h @ W2 (MFMA -> bf16), h3 = A_norm @ hw fused relu+LN
    {
        dim3 grid((N_NODES + 127) / 128, HID2 / 128);
        mfma_gemm128<HID1, HID2, HID1><<<grid, 256, 0, stream>>>(hb, W2T, hwb);
    }
    agg256_ln_kernel<<<(N_NODES + 3) / 4, 256, 0, stream>>>(
        rowptr, csr_src, csr_norm, dinv, hwb, b2, g2, be2, h3);

    // 5. pool + fc
    bounds_kernel<<<1, 64, 0, stream>>>(bat, gstart);
    hipMemsetAsync(pooled, 0, NUM_GRAPHS * HID2 * sizeof(float), stream);
    {
        dim3 grid(NUM_GRAPHS, 16);
        pool2_kernel<<<grid, 256, 0, stream>>>(h3, gstart, pooled);
    }
    fc_kernel<<<1, 64, 0, stream>>>(pooled, gstart, Wfc, bfc, fcO);
}